// Round 1
// baseline (258.811 us; speedup 1.0000x reference)
//
#include <hip/hip_runtime.h>
#include <cmath>

#define NPTS 262144
#define NLVL 16
#define TBL  524288u
#define TMASK 524287u
#define TPB  256   // points per block (k2)
#define NQ   7     // levels 0..6 oct-densified

typedef __attribute__((ext_vector_type(8))) short short8;
typedef __attribute__((ext_vector_type(4))) float f32x4;

struct ResArr { float r[NLVL]; };
struct QuadInfo { int off[NQ]; int dim[NQ]; };   // off in 32B oct-entry units

__device__ __forceinline__ unsigned short f2bf(float f) {
    union { float f; unsigned u; } v; v.f = f;
    unsigned r = v.u + 0x7FFFu + ((v.u >> 16) & 1u);   // RNE
    return (unsigned short)(r >> 16);
}
__device__ __forceinline__ float blo(unsigned u) {
    union { unsigned v; float f; } x; x.v = u << 16; return x.f;
}
__device__ __forceinline__ float bhi(unsigned u) {
    union { unsigned v; float f; } x; x.v = u & 0xffff0000u; return x.f;
}
__device__ __forceinline__ unsigned packbf(float a, float b) {
    return (unsigned)f2bf(a) | ((unsigned)f2bf(b) << 16);
}

#define MFMA(a,b,c) __builtin_amdgcn_mfma_f32_16x16x32_bf16((a),(b),(c),0,0,0)

// ---------------------------------------------------------------------------
// Prep kernel: blockIdx.y = level 0..6 -> OCT arrays (32B/cell = all 8 corners
// of cell (x,y,z): lo = y/z-quad at slab x, hi = y/z-quad at slab x+1).
// Thread computes its 16B quad once and stores it twice (lo of cell x, hi of
// cell x-1) -> main kernel's two 16B loads share one 64B line (2nd is L1 hit).
// l==7: block 0 packs MLP weights/biases; blocks 1..1024 repack coords->float4.
// ---------------------------------------------------------------------------
__global__ __launch_bounds__(256) void prep_k(
    const float* __restrict__ emb,
    const float* __restrict__ coords,
    float4* __restrict__ c4,
    uint4* __restrict__ oct, QuadInfo qi,
    const float* __restrict__ dw1, const float* __restrict__ db1,
    const float* __restrict__ dw2, const float* __restrict__ db2,
    const float* __restrict__ cw1, const float* __restrict__ cb1,
    const float* __restrict__ cw2, const float* __restrict__ cb2,
    const float* __restrict__ cw3, const float* __restrict__ cb3,
    const float* __restrict__ cw4, const float* __restrict__ cb4,
    unsigned short* __restrict__ wpk, float* __restrict__ bpk)
{
    const int l = blockIdx.y;
    const int tid = threadIdx.x;

    if (l == 7) {
        if (blockIdx.x == 0) {
            const int wid  = tid >> 6;
            const int lane = tid & 63;
            const int m16  = lane & 15;
            const int q    = lane >> 4;
            const unsigned char MAT[28] = {0,0,0,0, 1,1, 2,2,2,2, 3,3,3,3,3,3,3,3, 4,4,4,4,4,4,4,4, 5,5};
            const unsigned char K0 [28] = {0,0,0,0, 0,32, 0,0,0,0, 0,0,0,0,32,32,32,32, 0,0,0,0,32,32,32,32, 0,32};
            const unsigned char N0 [28] = {0,16,32,48, 0,0, 0,16,32,48, 0,16,32,48,0,16,32,48, 0,16,32,48,0,16,32,48, 0,0};
            #pragma unroll
            for (int s = 0; s < 28; ++s) {
                if ((s & 3) == wid) {
                    const int mat = MAT[s];
                    const float* src = mat==0?dw1 : mat==1?dw2 : mat==2?cw1 : mat==3?cw2 : mat==4?cw3 : cw4;
                    const int fan = (mat==1) ? 16 : (mat==5) ? 3 : 64;
                    const int k = (int)K0[s] + q*8;
                    const int n = (int)N0[s] + m16;
                    unsigned short u[8];
                    #pragma unroll
                    for (int j = 0; j < 8; ++j) {
                        float v = 0.f;
                        if (mat != 5 || n < 3) v = src[(k+j)*fan + n];
                        u[j] = f2bf(v);
                    }
                    unsigned* w32 = (unsigned*)(wpk + s*512 + lane*8);
                    w32[0] = (unsigned)u[0] | ((unsigned)u[1] << 16);
                    w32[1] = (unsigned)u[2] | ((unsigned)u[3] << 16);
                    w32[2] = (unsigned)u[4] | ((unsigned)u[5] << 16);
                    w32[3] = (unsigned)u[6] | ((unsigned)u[7] << 16);
                }
            }
            {
                int t = tid;
                if      (t <  64) bpk[t] = db1[t];
                else if (t <  80) bpk[t] = db2[t-64];
                else if (t < 144) bpk[t] = cb1[t-80];
                else if (t < 208) bpk[t] = cb2[t-144];
            }
            if (tid < 80) {
                int t = tid + 208;
                if (t < 272) bpk[t] = cb3[t-208];
                else         bpk[t] = (t-272 < 3) ? cb4[t-272] : 0.f;
            }
        } else if (blockIdx.x <= 1024) {
            // coords -> float4 repack (one dwordx4 load/pt in hash kernel
            // instead of 3 stride-12 scalar dwords: ~0.56 -> 0.125 req/pt)
            const int p = (blockIdx.x - 1) * 256 + tid;
            float4 c;
            c.x = coords[3*p]; c.y = coords[3*p+1]; c.z = coords[3*p+2]; c.w = 0.f;
            c4[p] = c;
        }
        return;
    }

    const int t = blockIdx.x * 256 + tid;
    const int D = qi.dim[l];
    if (t >= D*D*D) return;
    const int DD = D*D;
    const unsigned z = (unsigned)t % (unsigned)D;
    const unsigned rem = (unsigned)t / (unsigned)D;
    const unsigned y = rem % (unsigned)D;

    const float2* __restrict__ emb2 = (const float2*)emb;
    const unsigned base = (unsigned)l * TBL;
    const unsigned x = rem / (unsigned)D;
    const unsigned hy0 = y*2654435761u, hy1 = (y+1u)*2654435761u;
    const unsigned hz0 = z*805459861u,  hz1 = (z+1u)*805459861u;

    const float2 a = emb2[base + ((x^hy0^hz0)&TMASK)];
    const float2 b = emb2[base + ((x^hy0^hz1)&TMASK)];
    const float2 c = emb2[base + ((x^hy1^hz0)&TMASK)];
    const float2 d = emb2[base + ((x^hy1^hz1)&TMASK)];

    uint4 q;
    q.x = packbf(a.x, a.y);
    q.y = packbf(b.x, b.y);
    q.z = packbf(c.x, c.y);
    q.w = packbf(d.x, d.y);

    const int e = qi.off[l] + t;
    oct[2*e] = q;                          // lo half of cell (x,y,z)
    if (t >= DD)
        oct[2*(e - DD) + 1] = q;           // hi half of cell (x-1,y,z)
}

// ---------------------------------------------------------------------------
// Kernel 1: hash-grid encode, cost-balanced XCD schedule.
// grid = 11008 blocks; xcd = b&7, s = b>>3 in [0,1376).
//  s < 1024        : hashed level (7+xcd), point chunk s
//  1024 <= s <1152 : l15 eighth
//  s >= 1152       : oct g = xcd*224+(s-1152): l=g>>8, c=g&255
// Oct path: 1 L2 request/pt (2nd 16B load is an L1 hit, same 64B line).
// Per-XCD L2 requests ~2.45M (was 2.82M): predict ~90us at 13.1 req/cy.
// ---------------------------------------------------------------------------
__global__ __launch_bounds__(256) void hash_encode_k(
    const float4* __restrict__ c4,
    const float* __restrict__ emb,
    const uint4* __restrict__ oct,
    unsigned* __restrict__ featws,
    ResArr res, QuadInfo qi)
{
    const int tid = threadIdx.x;
    const int b   = blockIdx.x;
    const int xcd = b & 7;
    const int s   = b >> 3;

    if (s < 1152) {
        // -------- hashed path --------
        int l, p;
        if (s < 1024) {
            l = 7 + xcd;
            p = s * 256 + tid;
        } else {
            l = 15;
            p = xcd * 32768 + (s - 1024) * 256 + tid;
        }

        const float4 cc = c4[p];
        const float r = res.r[l];
        const float px = cc.x*r, py = cc.y*r, pz = cc.z*r;
        const float fpx = floorf(px), fpy = floorf(py), fpz = floorf(pz);
        const float fx = px-fpx, fy = py-fpy, fz = pz-fpz;
        const unsigned ix=(unsigned)fpx, iy=(unsigned)fpy, iz=(unsigned)fpz;
        const unsigned hx0=ix,             hx1=ix+1u;
        const unsigned hy0=iy*2654435761u, hy1=(iy+1u)*2654435761u;
        const unsigned hz0=iz*805459861u,  hz1=(iz+1u)*805459861u;
        const unsigned base = (unsigned)l * TBL;
        const float2* __restrict__ emb2 = (const float2*)emb;

        const float2 f000 = emb2[base + ((hx0^hy0^hz0)&TMASK)];
        const float2 f001 = emb2[base + ((hx0^hy0^hz1)&TMASK)];
        const float2 f010 = emb2[base + ((hx0^hy1^hz0)&TMASK)];
        const float2 f011 = emb2[base + ((hx0^hy1^hz1)&TMASK)];
        const float2 f100 = emb2[base + ((hx1^hy0^hz0)&TMASK)];
        const float2 f101 = emb2[base + ((hx1^hy0^hz1)&TMASK)];
        const float2 f110 = emb2[base + ((hx1^hy1^hz0)&TMASK)];
        const float2 f111 = emb2[base + ((hx1^hy1^hz1)&TMASK)];

        const float wx0=1.f-fx, wy0=1.f-fy, wz0=1.f-fz;
        float o0, o1;
        o0 = wx0*wy0*wz0*f000.x;                 o1 = wx0*wy0*wz0*f000.y;
        o0 = fmaf(wx0*wy0*fz,  f001.x, o0);      o1 = fmaf(wx0*wy0*fz,  f001.y, o1);
        o0 = fmaf(wx0*fy*wz0,  f010.x, o0);      o1 = fmaf(wx0*fy*wz0,  f010.y, o1);
        o0 = fmaf(wx0*fy*fz,   f011.x, o0);      o1 = fmaf(wx0*fy*fz,   f011.y, o1);
        o0 = fmaf(fx*wy0*wz0,  f100.x, o0);      o1 = fmaf(fx*wy0*wz0,  f100.y, o1);
        o0 = fmaf(fx*wy0*fz,   f101.x, o0);      o1 = fmaf(fx*wy0*fz,   f101.y, o1);
        o0 = fmaf(fx*fy*wz0,   f110.x, o0);      o1 = fmaf(fx*fy*wz0,   f110.y, o1);
        o0 = fmaf(fx*fy*fz,    f111.x, o0);      o1 = fmaf(fx*fy*fz,    f111.y, o1);

        featws[(size_t)l * NPTS + p] = packbf(o0, o1);
    } else {
        // -------- oct path: 4 points/thread, 1 line/point --------
        const int g  = xcd * 224 + (s - 1152);    // 0..1791
        const int l  = g >> 8;                    // 0..6
        const int c  = g & 255;
        const int D  = qi.dim[l];
        const int off = qi.off[l];
        const float r = res.r[l];

        int   pidx[4];
        uint4 qA[4], qB[4];
        float fxa[4], fya[4], fza[4];
        #pragma unroll
        for (int k = 0; k < 4; ++k) {
            const int p = c*1024 + k*256 + tid;
            pidx[k] = p;
            const float4 cc = c4[p];
            const float px = cc.x*r, py = cc.y*r, pz = cc.z*r;
            const float fpx = floorf(px), fpy = floorf(py), fpz = floorf(pz);
            fxa[k] = px-fpx; fya[k] = py-fpy; fza[k] = pz-fpz;
            const int ix=(int)fpx, iy=(int)fpy, iz=(int)fpz;
            const int v0 = off + (ix*D + iy)*D + iz;
            qA[k] = oct[2*v0];
            qB[k] = oct[2*v0 + 1];
        }
        #pragma unroll
        for (int k = 0; k < 4; ++k) {
            const float fx = fxa[k], fy = fya[k], fz = fza[k];
            const float wx0=1.f-fx, wy0=1.f-fy, wz0=1.f-fz;
            const float w000=wx0*wy0*wz0, w001=wx0*wy0*fz;
            const float w010=wx0*fy*wz0,  w011=wx0*fy*fz;
            const float w100=fx*wy0*wz0,  w101=fx*wy0*fz;
            const float w110=fx*fy*wz0,   w111=fx*fy*fz;
            float o0, o1;
            o0 = w000*blo(qA[k].x);              o1 = w000*bhi(qA[k].x);
            o0 = fmaf(w001, blo(qA[k].y), o0);   o1 = fmaf(w001, bhi(qA[k].y), o1);
            o0 = fmaf(w010, blo(qA[k].z), o0);   o1 = fmaf(w010, bhi(qA[k].z), o1);
            o0 = fmaf(w011, blo(qA[k].w), o0);   o1 = fmaf(w011, bhi(qA[k].w), o1);
            o0 = fmaf(w100, blo(qB[k].x), o0);   o1 = fmaf(w100, bhi(qB[k].x), o1);
            o0 = fmaf(w101, blo(qB[k].y), o0);   o1 = fmaf(w101, bhi(qB[k].y), o1);
            o0 = fmaf(w110, blo(qB[k].z), o0);   o1 = fmaf(w110, bhi(qB[k].z), o1);
            o0 = fmaf(w111, blo(qB[k].w), o0);   o1 = fmaf(w111, bhi(qB[k].w), o1);
            featws[(size_t)l * NPTS + pidx[k]] = packbf(o0, o1);
        }
    }
}

// ---------------------------------------------------------------------------
// Kernel 2: MFMA MLP chain. 256 points/block. LDS ~59KB -> 2 blocks/CU.
// (unchanged this round)
// ---------------------------------------------------------------------------
__global__ __launch_bounds__(256, 2) void mlp_mfma_k(
    const unsigned* __restrict__ featws,
    const unsigned short* __restrict__ wpk,
    const float* __restrict__ bpk,
    const float* __restrict__ dirs,
    float* __restrict__ out)
{
    const int tid  = threadIdx.x;
    const int wid  = tid >> 6;
    const int lane = tid & 63;
    const int m16  = lane & 15;
    const int q    = lane >> 4;

    __shared__ __align__(16) unsigned short wlds[28 * 512];
    __shared__ float blds[288];
    __shared__ __align__(16) unsigned short featL[TPB * 40];   // [pt][32+8 pad] bf16
    __shared__ __align__(16) unsigned short actL[4 * 16 * 72]; // per-wave [16][64+8] bf16

    {
        uint4* dst = (uint4*)wlds;
        const uint4* srcv = (const uint4*)wpk;   // 1792 uint4
        #pragma unroll
        for (int j = 0; j < 7; ++j) dst[j*256 + tid] = srcv[j*256 + tid];
        if (tid < 256) blds[tid] = bpk[tid];             // biases 0..255
        if (tid < 32)  blds[256 + tid] = bpk[256 + tid]; // 256..287 (cb3 tail + cb4)
    }

    const int pbase = blockIdx.x * TPB;
    unsigned* fL32 = (unsigned*)featL;        // row stride 20 uints
    #pragma unroll
    for (int j = 0; j < 16; ++j) {
        const int idx  = j*256 + tid;         // 0..4095
        const int l    = idx >> 8;
        const int ploc = idx & 255;
        fL32[ploc*20 + l] = featws[(size_t)l * NPTS + pbase + ploc];
    }
    __syncthreads();

    unsigned short* aw = actL + wid*1152;     // 16 x 72
    const short8* wfr = (const short8*)wlds;  // B(s) = wfr[s*64 + lane]

    #pragma unroll
    for (int iter = 0; iter < 4; ++iter) {
        const int tile = wid + 4*iter;
        const int loc0 = tile*16;
        const int p0g  = pbase + loc0;

        // ---- density L1: feat(32) -> 64, relu ----
        short8 a0 = *(const short8*)(featL + (loc0+m16)*40 + q*8);
        f32x4 acc[4];
        #pragma unroll
        for (int nc = 0; nc < 4; ++nc) {
            const float b = blds[nc*16 + m16];
            acc[nc] = (f32x4){b,b,b,b};
            acc[nc] = MFMA(a0, wfr[nc*64 + lane], acc[nc]);
        }
        #pragma unroll
        for (int nc = 0; nc < 4; ++nc)
            #pragma unroll
            for (int r = 0; r < 4; ++r)
                aw[(q*4+r)*72 + nc*16 + m16] = f2bf(fmaxf(acc[nc][r], 0.f));

        // ---- density L2: 64 -> 16 (no act) ----
        short8 ad0 = *(const short8*)(aw + m16*72 + q*8);
        short8 ad1 = *(const short8*)(aw + m16*72 + 32 + q*8);
        f32x4 dob;
        { const float b = blds[64 + m16]; dob = (f32x4){b,b,b,b}; }
        dob = MFMA(ad0, wfr[4*64 + lane], dob);
        dob = MFMA(ad1, wfr[5*64 + lane], dob);

        if (m16 == 0) {
            #pragma unroll
            for (int r = 0; r < 4; ++r) out[p0g + q*4 + r] = expf(dob[r]);
        }

        // ---- build inp = [SH(16) | dob(16)] ----
        #pragma unroll
        for (int r = 0; r < 4; ++r)
            aw[(q*4+r)*72 + 16 + m16] = f2bf(dob[r]);
        {
            const int pg = p0g + m16;
            const float dx0 = dirs[3*pg], dy0 = dirs[3*pg+1], dz0 = dirs[3*pg+2];
            const float inv = 1.f / sqrtf(dx0*dx0 + dy0*dy0 + dz0*dz0);
            float x = dx0*inv, y = dy0*inv, z = dz0*inv;
            x = ((x+1.f)*0.5f)*2.f - 1.f;
            y = ((y+1.f)*0.5f)*2.f - 1.f;
            z = ((z+1.f)*0.5f)*2.f - 1.f;
            float s0, s1, s2, s3;
            switch (q) {
            case 0: s0 = 0.28209479177387814f;
                    s1 = -0.48860251190291987f*y;
                    s2 =  0.48860251190291987f*z;
                    s3 = -0.48860251190291987f*x; break;
            case 1: s0 =  1.0925484305920792f*x*y;
                    s1 = -1.0925484305920792f*y*z;
                    s2 =  0.94617469575756f*z*z - 0.31539156525252f;
                    s3 = -1.0925484305920792f*x*z; break;
            case 2: s0 =  0.5462742152960396f*(x*x - y*y);
                    s1 =  0.5900435899266435f*y*(-3.f*x*x + y*y);
                    s2 =  2.890611442640554f*x*y*z;
                    s3 =  0.4570457994644657f*y*(1.f - 5.f*z*z); break;
            default:s0 =  0.3731763325901154f*z*(5.f*z*z - 3.f);
                    s1 =  0.4570457994644657f*x*(1.f - 5.f*z*z);
                    s2 =  1.445305721320277f*z*(x*x - y*y);
                    s3 =  0.5900435899266435f*x*(x*x - 3.f*y*y); break;
            }
            unsigned* ip = (unsigned*)(aw + m16*72 + q*4);
            ip[0] = packbf(s0, s1);
            ip[1] = packbf(s2, s3);
        }

        // ---- color L1: inp(32) -> 64, relu ----
        short8 ac0 = *(const short8*)(aw + m16*72 + q*8);
        #pragma unroll
        for (int nc = 0; nc < 4; ++nc) {
            const float b = blds[80 + nc*16 + m16];
            acc[nc] = (f32x4){b,b,b,b};
            acc[nc] = MFMA(ac0, wfr[(6+nc)*64 + lane], acc[nc]);
        }
        #pragma unroll
        for (int nc = 0; nc < 4; ++nc)
            #pragma unroll
            for (int r = 0; r < 4; ++r)
                aw[(q*4+r)*72 + nc*16 + m16] = f2bf(fmaxf(acc[nc][r], 0.f));

        // ---- color L2: 64 -> 64, relu ----
        short8 a20 = *(const short8*)(aw + m16*72 + q*8);
        short8 a21 = *(const short8*)(aw + m16*72 + 32 + q*8);
        #pragma unroll
        for (int nc = 0; nc < 4; ++nc) {
            const float b = blds[144 + nc*16 + m16];
            acc[nc] = (f32x4){b,b,b,b};
            acc[nc] = MFMA(a20, wfr[(10+nc)*64 + lane], acc[nc]);
            acc[nc] = MFMA(a21, wfr[(14+nc)*64 + lane], acc[nc]);
        }
        #pragma unroll
        for (int nc = 0; nc < 4; ++nc)
            #pragma unroll
            for (int r = 0; r < 4; ++r)
                aw[(q*4+r)*72 + nc*16 + m16] = f2bf(fmaxf(acc[nc][r], 0.f));

        // ---- color L3: 64 -> 64, relu ----
        short8 a30 = *(const short8*)(aw + m16*72 + q*8);
        short8 a31 = *(const short8*)(aw + m16*72 + 32 + q*8);
        #pragma unroll
        for (int nc = 0; nc < 4; ++nc) {
            const float b = blds[208 + nc*16 + m16];
            acc[nc] = (f32x4){b,b,b,b};
            acc[nc] = MFMA(a30, wfr[(18+nc)*64 + lane], acc[nc]);
            acc[nc] = MFMA(a31, wfr[(22+nc)*64 + lane], acc[nc]);
        }
        #pragma unroll
        for (int nc = 0; nc < 4; ++nc)
            #pragma unroll
            for (int r = 0; r < 4; ++r)
                aw[(q*4+r)*72 + nc*16 + m16] = f2bf(fmaxf(acc[nc][r], 0.f));

        // ---- color L4: 64 -> 3 (padded to 16), sigmoid ----
        short8 a40 = *(const short8*)(aw + m16*72 + q*8);
        short8 a41 = *(const short8*)(aw + m16*72 + 32 + q*8);
        f32x4 c4v;
        { const float b = blds[272 + m16]; c4v = (f32x4){b,b,b,b}; }
        c4v = MFMA(a40, wfr[26*64 + lane], c4v);
        c4v = MFMA(a41, wfr[27*64 + lane], c4v);
        if (m16 < 3) {
            #pragma unroll
            for (int r = 0; r < 4; ++r)
                out[NPTS + 3*(p0g + q*4 + r) + m16] = 1.f / (1.f + expf(-c4v[r]));
        }
    }
}

extern "C" void kernel_launch(void* const* d_in, const int* in_sizes, int n_in,
                              void* d_out, int out_size, void* d_ws, size_t ws_size,
                              hipStream_t stream)
{
    // RES must bit-match numpy: floor(16 * b**l) in f64, b = exp((ln512-ln16)/15).
    ResArr res;
    const double b = exp((log(512.0) - log(16.0)) / 15.0);
    for (int l = 0; l < NLVL; ++l)
        res.r[l] = (float)floor(16.0 * pow(b, (double)l));

    // oct arrays for levels 0..6: dim = res+1
    QuadInfo qi;
    int off = 0, maxn = 0;
    for (int l = 0; l < NQ; ++l) {
        const int D = (int)res.r[l] + 1;
        qi.dim[l] = D;
        qi.off[l] = off;
        off += D*D*D;
        if (D*D*D > maxn) maxn = D*D*D;
    }

    // ws: featws 16.8MB | oct (543,884*32B = 17.4MB) | c4 4MB | wpk 28KB | bpk 1.2KB
    unsigned*       featws = (unsigned*)d_ws;
    uint4*          oct    = (uint4*)((char*)d_ws + (size_t)NLVL * NPTS * 4);
    float4*         c4     = (float4*)((char*)oct + (size_t)off * 32);
    unsigned short* wpk    = (unsigned short*)((char*)c4 + (size_t)NPTS * 16);
    float*          bpk    = (float*)((char*)wpk + 28 * 512 * 2);

    prep_k<<<dim3((maxn + 255)/256, 8), 256, 0, stream>>>(
        (const float*)d_in[2],   // embeddings
        (const float*)d_in[0],   // coords
        c4, oct, qi,
        (const float*)d_in[3],  (const float*)d_in[4],
        (const float*)d_in[5],  (const float*)d_in[6],
        (const float*)d_in[7],  (const float*)d_in[8],
        (const float*)d_in[9],  (const float*)d_in[10],
        (const float*)d_in[11], (const float*)d_in[12],
        (const float*)d_in[13], (const float*)d_in[14],
        wpk, bpk);

    hash_encode_k<<<11008, 256, 0, stream>>>(
        c4,
        (const float*)d_in[2],   // embeddings
        oct, featws, res, qi);

    mlp_mfma_k<<<NPTS/TPB, 256, 0, stream>>>(
        featws, wpk, bpk,
        (const float*)d_in[1],   // directions
        (float*)d_out);
}

// Round 2
// 247.103 us; speedup vs baseline: 1.0474x; 1.0474x over previous
//
#include <hip/hip_runtime.h>
#include <cmath>

#define NPTS 262144
#define NLVL 16
#define TBL  524288u
#define TMASK 524287u
#define TPB  256   // points per block (k2)
#define NQ   7     // levels 0..6 oct-densified

typedef __attribute__((ext_vector_type(8))) short short8;
typedef __attribute__((ext_vector_type(4))) float f32x4;

struct ResArr { float r[NLVL]; };
struct QuadInfo { int off[NQ]; int dim[NQ]; };   // off in 32B oct-entry units

__device__ __forceinline__ unsigned short f2bf(float f) {
    union { float f; unsigned u; } v; v.f = f;
    unsigned r = v.u + 0x7FFFu + ((v.u >> 16) & 1u);   // RNE
    return (unsigned short)(r >> 16);
}
__device__ __forceinline__ float blo(unsigned u) {
    union { unsigned v; float f; } x; x.v = u << 16; return x.f;
}
__device__ __forceinline__ float bhi(unsigned u) {
    union { unsigned v; float f; } x; x.v = u & 0xffff0000u; return x.f;
}
__device__ __forceinline__ unsigned packbf(float a, float b) {
    return (unsigned)f2bf(a) | ((unsigned)f2bf(b) << 16);
}

#define MFMA(a,b,c) __builtin_amdgcn_mfma_f32_16x16x32_bf16((a),(b),(c),0,0,0)

// ---------------------------------------------------------------------------
// Prep kernel: blockIdx.y = level 0..6 -> OCT arrays (32B/cell = all 8 corners
// of cell (x,y,z): lo = y/z-quad at slab x, hi = y/z-quad at slab x+1).
// l==7: block 0 packs MLP weights/biases; blocks 1..1024 repack coords->float4.
// ---------------------------------------------------------------------------
__global__ __launch_bounds__(256) void prep_k(
    const float* __restrict__ emb,
    const float* __restrict__ coords,
    float4* __restrict__ c4,
    uint4* __restrict__ oct, QuadInfo qi,
    const float* __restrict__ dw1, const float* __restrict__ db1,
    const float* __restrict__ dw2, const float* __restrict__ db2,
    const float* __restrict__ cw1, const float* __restrict__ cb1,
    const float* __restrict__ cw2, const float* __restrict__ cb2,
    const float* __restrict__ cw3, const float* __restrict__ cb3,
    const float* __restrict__ cw4, const float* __restrict__ cb4,
    unsigned short* __restrict__ wpk, float* __restrict__ bpk)
{
    const int l = blockIdx.y;
    const int tid = threadIdx.x;

    if (l == 7) {
        if (blockIdx.x == 0) {
            const int wid  = tid >> 6;
            const int lane = tid & 63;
            const int m16  = lane & 15;
            const int q    = lane >> 4;
            const unsigned char MAT[28] = {0,0,0,0, 1,1, 2,2,2,2, 3,3,3,3,3,3,3,3, 4,4,4,4,4,4,4,4, 5,5};
            const unsigned char K0 [28] = {0,0,0,0, 0,32, 0,0,0,0, 0,0,0,0,32,32,32,32, 0,0,0,0,32,32,32,32, 0,32};
            const unsigned char N0 [28] = {0,16,32,48, 0,0, 0,16,32,48, 0,16,32,48,0,16,32,48, 0,16,32,48,0,16,32,48, 0,0};
            #pragma unroll
            for (int s = 0; s < 28; ++s) {
                if ((s & 3) == wid) {
                    const int mat = MAT[s];
                    const float* src = mat==0?dw1 : mat==1?dw2 : mat==2?cw1 : mat==3?cw2 : mat==4?cw3 : cw4;
                    const int fan = (mat==1) ? 16 : (mat==5) ? 3 : 64;
                    const int k = (int)K0[s] + q*8;
                    const int n = (int)N0[s] + m16;
                    unsigned short u[8];
                    #pragma unroll
                    for (int j = 0; j < 8; ++j) {
                        float v = 0.f;
                        if (mat != 5 || n < 3) v = src[(k+j)*fan + n];
                        u[j] = f2bf(v);
                    }
                    unsigned* w32 = (unsigned*)(wpk + s*512 + lane*8);
                    w32[0] = (unsigned)u[0] | ((unsigned)u[1] << 16);
                    w32[1] = (unsigned)u[2] | ((unsigned)u[3] << 16);
                    w32[2] = (unsigned)u[4] | ((unsigned)u[5] << 16);
                    w32[3] = (unsigned)u[6] | ((unsigned)u[7] << 16);
                }
            }
            {
                int t = tid;
                if      (t <  64) bpk[t] = db1[t];
                else if (t <  80) bpk[t] = db2[t-64];
                else if (t < 144) bpk[t] = cb1[t-80];
                else if (t < 208) bpk[t] = cb2[t-144];
            }
            if (tid < 80) {
                int t = tid + 208;
                if (t < 272) bpk[t] = cb3[t-208];
                else         bpk[t] = (t-272 < 3) ? cb4[t-272] : 0.f;
            }
        } else if (blockIdx.x <= 1024) {
            const int p = (blockIdx.x - 1) * 256 + tid;
            float4 c;
            c.x = coords[3*p]; c.y = coords[3*p+1]; c.z = coords[3*p+2]; c.w = 0.f;
            c4[p] = c;
        }
        return;
    }

    const int t = blockIdx.x * 256 + tid;
    const int D = qi.dim[l];
    if (t >= D*D*D) return;
    const int DD = D*D;
    const unsigned z = (unsigned)t % (unsigned)D;
    const unsigned rem = (unsigned)t / (unsigned)D;
    const unsigned y = rem % (unsigned)D;

    const float2* __restrict__ emb2 = (const float2*)emb;
    const unsigned base = (unsigned)l * TBL;
    const unsigned x = rem / (unsigned)D;
    const unsigned hy0 = y*2654435761u, hy1 = (y+1u)*2654435761u;
    const unsigned hz0 = z*805459861u,  hz1 = (z+1u)*805459861u;

    const float2 a = emb2[base + ((x^hy0^hz0)&TMASK)];
    const float2 b = emb2[base + ((x^hy0^hz1)&TMASK)];
    const float2 c = emb2[base + ((x^hy1^hz0)&TMASK)];
    const float2 d = emb2[base + ((x^hy1^hz1)&TMASK)];

    uint4 q;
    q.x = packbf(a.x, a.y);
    q.y = packbf(b.x, b.y);
    q.z = packbf(c.x, c.y);
    q.w = packbf(d.x, d.y);

    const int e = qi.off[l] + t;
    oct[2*e] = q;                          // lo half of cell (x,y,z)
    if (t >= DD)
        oct[2*(e - DD) + 1] = q;           // hi half of cell (x-1,y,z)
}

// ---------------------------------------------------------------------------
// Kernel 1: hash-grid encode, cost-balanced XCD schedule.
// grid = 11008 blocks; xcd = b&7, s = b>>3 in [0,1376).
//  s < 1024        : hashed level (7+xcd), point chunk s
//  1024 <= s <1152 : l15 eighth
//  s >= 1152       : oct g = xcd*224+(s-1152): l=g>>8, c=g&255
// Hashed path uses x-parity pairing: PRIMES[0]==1 and XOR mixing mean the two
// x-corners hash to indices h and h^(x^(x+1)). For even x the pair is an
// aligned float4 -> 4x16B pair loads serve x0 for ALL lanes + x1 for even-x
// lanes; 4 extra 8B gathers exec-masked to odd-x lanes. 6 req/pt avg (was 8).
// ---------------------------------------------------------------------------
__global__ __launch_bounds__(256) void hash_encode_k(
    const float4* __restrict__ c4,
    const float* __restrict__ emb,
    const uint4* __restrict__ oct,
    unsigned* __restrict__ featws,
    ResArr res, QuadInfo qi)
{
    const int tid = threadIdx.x;
    const int b   = blockIdx.x;
    const int xcd = b & 7;
    const int s   = b >> 3;

    if (s < 1152) {
        // -------- hashed path --------
        int l, p;
        if (s < 1024) {
            l = 7 + xcd;
            p = s * 256 + tid;
        } else {
            l = 15;
            p = xcd * 32768 + (s - 1024) * 256 + tid;
        }

        const float4 cc = c4[p];
        const float r = res.r[l];
        const float px = cc.x*r, py = cc.y*r, pz = cc.z*r;
        const float fpx = floorf(px), fpy = floorf(py), fpz = floorf(pz);
        const float fx = px-fpx, fy = py-fpy, fz = pz-fpz;
        const unsigned ix=(unsigned)fpx, iy=(unsigned)fpy, iz=(unsigned)fpz;
        const unsigned hy0=iy*2654435761u, hy1=(iy+1u)*2654435761u;
        const unsigned hz0=iz*805459861u,  hz1=(iz+1u)*805459861u;
        const unsigned base  = (unsigned)l * TBL;          // float2 units
        const unsigned base4 = (unsigned)l * (TBL >> 1);   // float4 units
        const float2* __restrict__ emb2 = (const float2*)emb;
        const float4* __restrict__ emb4 = (const float4*)emb;

        const unsigned m = ix ^ (ix + 1u);                 // 1 iff ix even
        const unsigned h00 = (ix^hy0^hz0) & TMASK;
        const unsigned h01 = (ix^hy0^hz1) & TMASK;
        const unsigned h10 = (ix^hy1^hz0) & TMASK;
        const unsigned h11 = (ix^hy1^hz1) & TMASK;

        // pair loads: float4 at h>>1 = entries {h&~1, h|1}
        const float4 p00 = emb4[base4 + (h00 >> 1)];
        const float4 p01 = emb4[base4 + (h01 >> 1)];
        const float4 p10 = emb4[base4 + (h10 >> 1)];
        const float4 p11 = emb4[base4 + (h11 >> 1)];

        // x0 corner = half selected by h&1; x1 corner = other half (iff m==1)
        float2 f000, f001, f010, f011, f100, f101, f110, f111;
        f000.x = (h00&1) ? p00.z : p00.x;  f000.y = (h00&1) ? p00.w : p00.y;
        f001.x = (h01&1) ? p01.z : p01.x;  f001.y = (h01&1) ? p01.w : p01.y;
        f010.x = (h10&1) ? p10.z : p10.x;  f010.y = (h10&1) ? p10.w : p10.y;
        f011.x = (h11&1) ? p11.z : p11.x;  f011.y = (h11&1) ? p11.w : p11.y;
        f100.x = (h00&1) ? p00.x : p00.z;  f100.y = (h00&1) ? p00.y : p00.w;
        f101.x = (h01&1) ? p01.x : p01.z;  f101.y = (h01&1) ? p01.y : p01.w;
        f110.x = (h10&1) ? p10.x : p10.z;  f110.y = (h10&1) ? p10.y : p10.w;
        f111.x = (h11&1) ? p11.x : p11.z;  f111.y = (h11&1) ? p11.y : p11.w;

        if (m != 1u) {
            // odd-x lanes: true x1 corners are h^m, not in the pair
            f100 = emb2[base + ((h00 ^ m) & TMASK)];
            f101 = emb2[base + ((h01 ^ m) & TMASK)];
            f110 = emb2[base + ((h10 ^ m) & TMASK)];
            f111 = emb2[base + ((h11 ^ m) & TMASK)];
        }

        const float wx0=1.f-fx, wy0=1.f-fy, wz0=1.f-fz;
        float o0, o1;
        o0 = wx0*wy0*wz0*f000.x;                 o1 = wx0*wy0*wz0*f000.y;
        o0 = fmaf(wx0*wy0*fz,  f001.x, o0);      o1 = fmaf(wx0*wy0*fz,  f001.y, o1);
        o0 = fmaf(wx0*fy*wz0,  f010.x, o0);      o1 = fmaf(wx0*fy*wz0,  f010.y, o1);
        o0 = fmaf(wx0*fy*fz,   f011.x, o0);      o1 = fmaf(wx0*fy*fz,   f011.y, o1);
        o0 = fmaf(fx*wy0*wz0,  f100.x, o0);      o1 = fmaf(fx*wy0*wz0,  f100.y, o1);
        o0 = fmaf(fx*wy0*fz,   f101.x, o0);      o1 = fmaf(fx*wy0*fz,   f101.y, o1);
        o0 = fmaf(fx*fy*wz0,   f110.x, o0);      o1 = fmaf(fx*fy*wz0,   f110.y, o1);
        o0 = fmaf(fx*fy*fz,    f111.x, o0);      o1 = fmaf(fx*fy*fz,    f111.y, o1);

        featws[(size_t)l * NPTS + p] = packbf(o0, o1);
    } else {
        // -------- oct path: 4 points/thread, 1 line/point --------
        const int g  = xcd * 224 + (s - 1152);    // 0..1791
        const int l  = g >> 8;                    // 0..6
        const int c  = g & 255;
        const int D  = qi.dim[l];
        const int off = qi.off[l];
        const float r = res.r[l];

        int   pidx[4];
        uint4 qA[4], qB[4];
        float fxa[4], fya[4], fza[4];
        #pragma unroll
        for (int k = 0; k < 4; ++k) {
            const int p = c*1024 + k*256 + tid;
            pidx[k] = p;
            const float4 cc = c4[p];
            const float px = cc.x*r, py = cc.y*r, pz = cc.z*r;
            const float fpx = floorf(px), fpy = floorf(py), fpz = floorf(pz);
            fxa[k] = px-fpx; fya[k] = py-fpy; fza[k] = pz-fpz;
            const int ix=(int)fpx, iy=(int)fpy, iz=(int)fpz;
            const int v0 = off + (ix*D + iy)*D + iz;
            qA[k] = oct[2*v0];
            qB[k] = oct[2*v0 + 1];
        }
        #pragma unroll
        for (int k = 0; k < 4; ++k) {
            const float fx = fxa[k], fy = fya[k], fz = fza[k];
            const float wx0=1.f-fx, wy0=1.f-fy, wz0=1.f-fz;
            const float w000=wx0*wy0*wz0, w001=wx0*wy0*fz;
            const float w010=wx0*fy*wz0,  w011=wx0*fy*fz;
            const float w100=fx*wy0*wz0,  w101=fx*wy0*fz;
            const float w110=fx*fy*wz0,   w111=fx*fy*fz;
            float o0, o1;
            o0 = w000*blo(qA[k].x);              o1 = w000*bhi(qA[k].x);
            o0 = fmaf(w001, blo(qA[k].y), o0);   o1 = fmaf(w001, bhi(qA[k].y), o1);
            o0 = fmaf(w010, blo(qA[k].z), o0);   o1 = fmaf(w010, bhi(qA[k].z), o1);
            o0 = fmaf(w011, blo(qA[k].w), o0);   o1 = fmaf(w011, bhi(qA[k].w), o1);
            o0 = fmaf(w100, blo(qB[k].x), o0);   o1 = fmaf(w100, bhi(qB[k].x), o1);
            o0 = fmaf(w101, blo(qB[k].y), o0);   o1 = fmaf(w101, bhi(qB[k].y), o1);
            o0 = fmaf(w110, blo(qB[k].z), o0);   o1 = fmaf(w110, bhi(qB[k].z), o1);
            o0 = fmaf(w111, blo(qB[k].w), o0);   o1 = fmaf(w111, bhi(qB[k].w), o1);
            featws[(size_t)l * NPTS + pidx[k]] = packbf(o0, o1);
        }
    }
}

// ---------------------------------------------------------------------------
// Kernel 2: MFMA MLP chain. 256 points/block. LDS ~59KB -> 2 blocks/CU.
// (unchanged)
// ---------------------------------------------------------------------------
__global__ __launch_bounds__(256, 2) void mlp_mfma_k(
    const unsigned* __restrict__ featws,
    const unsigned short* __restrict__ wpk,
    const float* __restrict__ bpk,
    const float* __restrict__ dirs,
    float* __restrict__ out)
{
    const int tid  = threadIdx.x;
    const int wid  = tid >> 6;
    const int lane = tid & 63;
    const int m16  = lane & 15;
    const int q    = lane >> 4;

    __shared__ __align__(16) unsigned short wlds[28 * 512];
    __shared__ float blds[288];
    __shared__ __align__(16) unsigned short featL[TPB * 40];   // [pt][32+8 pad] bf16
    __shared__ __align__(16) unsigned short actL[4 * 16 * 72]; // per-wave [16][64+8] bf16

    {
        uint4* dst = (uint4*)wlds;
        const uint4* srcv = (const uint4*)wpk;   // 1792 uint4
        #pragma unroll
        for (int j = 0; j < 7; ++j) dst[j*256 + tid] = srcv[j*256 + tid];
        if (tid < 256) blds[tid] = bpk[tid];             // biases 0..255
        if (tid < 32)  blds[256 + tid] = bpk[256 + tid]; // 256..287 (cb3 tail + cb4)
    }

    const int pbase = blockIdx.x * TPB;
    unsigned* fL32 = (unsigned*)featL;        // row stride 20 uints
    #pragma unroll
    for (int j = 0; j < 16; ++j) {
        const int idx  = j*256 + tid;         // 0..4095
        const int l    = idx >> 8;
        const int ploc = idx & 255;
        fL32[ploc*20 + l] = featws[(size_t)l * NPTS + pbase + ploc];
    }
    __syncthreads();

    unsigned short* aw = actL + wid*1152;     // 16 x 72
    const short8* wfr = (const short8*)wlds;  // B(s) = wfr[s*64 + lane]

    #pragma unroll
    for (int iter = 0; iter < 4; ++iter) {
        const int tile = wid + 4*iter;
        const int loc0 = tile*16;
        const int p0g  = pbase + loc0;

        // ---- density L1: feat(32) -> 64, relu ----
        short8 a0 = *(const short8*)(featL + (loc0+m16)*40 + q*8);
        f32x4 acc[4];
        #pragma unroll
        for (int nc = 0; nc < 4; ++nc) {
            const float b = blds[nc*16 + m16];
            acc[nc] = (f32x4){b,b,b,b};
            acc[nc] = MFMA(a0, wfr[nc*64 + lane], acc[nc]);
        }
        #pragma unroll
        for (int nc = 0; nc < 4; ++nc)
            #pragma unroll
            for (int r = 0; r < 4; ++r)
                aw[(q*4+r)*72 + nc*16 + m16] = f2bf(fmaxf(acc[nc][r], 0.f));

        // ---- density L2: 64 -> 16 (no act) ----
        short8 ad0 = *(const short8*)(aw + m16*72 + q*8);
        short8 ad1 = *(const short8*)(aw + m16*72 + 32 + q*8);
        f32x4 dob;
        { const float b = blds[64 + m16]; dob = (f32x4){b,b,b,b}; }
        dob = MFMA(ad0, wfr[4*64 + lane], dob);
        dob = MFMA(ad1, wfr[5*64 + lane], dob);

        if (m16 == 0) {
            #pragma unroll
            for (int r = 0; r < 4; ++r) out[p0g + q*4 + r] = expf(dob[r]);
        }

        // ---- build inp = [SH(16) | dob(16)] ----
        #pragma unroll
        for (int r = 0; r < 4; ++r)
            aw[(q*4+r)*72 + 16 + m16] = f2bf(dob[r]);
        {
            const int pg = p0g + m16;
            const float dx0 = dirs[3*pg], dy0 = dirs[3*pg+1], dz0 = dirs[3*pg+2];
            const float inv = 1.f / sqrtf(dx0*dx0 + dy0*dy0 + dz0*dz0);
            float x = dx0*inv, y = dy0*inv, z = dz0*inv;
            x = ((x+1.f)*0.5f)*2.f - 1.f;
            y = ((y+1.f)*0.5f)*2.f - 1.f;
            z = ((z+1.f)*0.5f)*2.f - 1.f;
            float s0, s1, s2, s3;
            switch (q) {
            case 0: s0 = 0.28209479177387814f;
                    s1 = -0.48860251190291987f*y;
                    s2 =  0.48860251190291987f*z;
                    s3 = -0.48860251190291987f*x; break;
            case 1: s0 =  1.0925484305920792f*x*y;
                    s1 = -1.0925484305920792f*y*z;
                    s2 =  0.94617469575756f*z*z - 0.31539156525252f;
                    s3 = -1.0925484305920792f*x*z; break;
            case 2: s0 =  0.5462742152960396f*(x*x - y*y);
                    s1 =  0.5900435899266435f*y*(-3.f*x*x + y*y);
                    s2 =  2.890611442640554f*x*y*z;
                    s3 =  0.4570457994644657f*y*(1.f - 5.f*z*z); break;
            default:s0 =  0.3731763325901154f*z*(5.f*z*z - 3.f);
                    s1 =  0.4570457994644657f*x*(1.f - 5.f*z*z);
                    s2 =  1.445305721320277f*z*(x*x - y*y);
                    s3 =  0.5900435899266435f*x*(x*x - 3.f*y*y); break;
            }
            unsigned* ip = (unsigned*)(aw + m16*72 + q*4);
            ip[0] = packbf(s0, s1);
            ip[1] = packbf(s2, s3);
        }

        // ---- color L1: inp(32) -> 64, relu ----
        short8 ac0 = *(const short8*)(aw + m16*72 + q*8);
        #pragma unroll
        for (int nc = 0; nc < 4; ++nc) {
            const float b = blds[80 + nc*16 + m16];
            acc[nc] = (f32x4){b,b,b,b};
            acc[nc] = MFMA(ac0, wfr[(6+nc)*64 + lane], acc[nc]);
        }
        #pragma unroll
        for (int nc = 0; nc < 4; ++nc)
            #pragma unroll
            for (int r = 0; r < 4; ++r)
                aw[(q*4+r)*72 + nc*16 + m16] = f2bf(fmaxf(acc[nc][r], 0.f));

        // ---- color L2: 64 -> 64, relu ----
        short8 a20 = *(const short8*)(aw + m16*72 + q*8);
        short8 a21 = *(const short8*)(aw + m16*72 + 32 + q*8);
        #pragma unroll
        for (int nc = 0; nc < 4; ++nc) {
            const float b = blds[144 + nc*16 + m16];
            acc[nc] = (f32x4){b,b,b,b};
            acc[nc] = MFMA(a20, wfr[(10+nc)*64 + lane], acc[nc]);
            acc[nc] = MFMA(a21, wfr[(14+nc)*64 + lane], acc[nc]);
        }
        #pragma unroll
        for (int nc = 0; nc < 4; ++nc)
            #pragma unroll
            for (int r = 0; r < 4; ++r)
                aw[(q*4+r)*72 + nc*16 + m16] = f2bf(fmaxf(acc[nc][r], 0.f));

        // ---- color L3: 64 -> 64, relu ----
        short8 a30 = *(const short8*)(aw + m16*72 + q*8);
        short8 a31 = *(const short8*)(aw + m16*72 + 32 + q*8);
        #pragma unroll
        for (int nc = 0; nc < 4; ++nc) {
            const float b = blds[208 + nc*16 + m16];
            acc[nc] = (f32x4){b,b,b,b};
            acc[nc] = MFMA(a30, wfr[(18+nc)*64 + lane], acc[nc]);
            acc[nc] = MFMA(a31, wfr[(22+nc)*64 + lane], acc[nc]);
        }
        #pragma unroll
        for (int nc = 0; nc < 4; ++nc)
            #pragma unroll
            for (int r = 0; r < 4; ++r)
                aw[(q*4+r)*72 + nc*16 + m16] = f2bf(fmaxf(acc[nc][r], 0.f));

        // ---- color L4: 64 -> 3 (padded to 16), sigmoid ----
        short8 a40 = *(const short8*)(aw + m16*72 + q*8);
        short8 a41 = *(const short8*)(aw + m16*72 + 32 + q*8);
        f32x4 c4v;
        { const float b = blds[272 + m16]; c4v = (f32x4){b,b,b,b}; }
        c4v = MFMA(a40, wfr[26*64 + lane], c4v);
        c4v = MFMA(a41, wfr[27*64 + lane], c4v);
        if (m16 < 3) {
            #pragma unroll
            for (int r = 0; r < 4; ++r)
                out[NPTS + 3*(p0g + q*4 + r) + m16] = 1.f / (1.f + expf(-c4v[r]));
        }
    }
}

extern "C" void kernel_launch(void* const* d_in, const int* in_sizes, int n_in,
                              void* d_out, int out_size, void* d_ws, size_t ws_size,
                              hipStream_t stream)
{
    // RES must bit-match numpy: floor(16 * b**l) in f64, b = exp((ln512-ln16)/15).
    ResArr res;
    const double b = exp((log(512.0) - log(16.0)) / 15.0);
    for (int l = 0; l < NLVL; ++l)
        res.r[l] = (float)floor(16.0 * pow(b, (double)l));

    // oct arrays for levels 0..6: dim = res+1
    QuadInfo qi;
    int off = 0, maxn = 0;
    for (int l = 0; l < NQ; ++l) {
        const int D = (int)res.r[l] + 1;
        qi.dim[l] = D;
        qi.off[l] = off;
        off += D*D*D;
        if (D*D*D > maxn) maxn = D*D*D;
    }

    // ws: featws 16.8MB | oct (543,884*32B = 17.4MB) | c4 4MB | wpk 28KB | bpk 1.2KB
    unsigned*       featws = (unsigned*)d_ws;
    uint4*          oct    = (uint4*)((char*)d_ws + (size_t)NLVL * NPTS * 4);
    float4*         c4     = (float4*)((char*)oct + (size_t)off * 32);
    unsigned short* wpk    = (unsigned short*)((char*)c4 + (size_t)NPTS * 16);
    float*          bpk    = (float*)((char*)wpk + 28 * 512 * 2);

    prep_k<<<dim3((maxn + 255)/256, 8), 256, 0, stream>>>(
        (const float*)d_in[2],   // embeddings
        (const float*)d_in[0],   // coords
        c4, oct, qi,
        (const float*)d_in[3],  (const float*)d_in[4],
        (const float*)d_in[5],  (const float*)d_in[6],
        (const float*)d_in[7],  (const float*)d_in[8],
        (const float*)d_in[9],  (const float*)d_in[10],
        (const float*)d_in[11], (const float*)d_in[12],
        (const float*)d_in[13], (const float*)d_in[14],
        wpk, bpk);

    hash_encode_k<<<11008, 256, 0, stream>>>(
        c4,
        (const float*)d_in[2],   // embeddings
        oct, featws, res, qi);

    mlp_mfma_k<<<NPTS/TPB, 256, 0, stream>>>(
        featws, wpk, bpk,
        (const float*)d_in[1],   // directions
        (float*)d_out);
}

// Round 3
// 239.535 us; speedup vs baseline: 1.0805x; 1.0316x over previous
//
#include <hip/hip_runtime.h>
#include <cmath>

#define NPTS 262144
#define NLVL 16
#define TBL  524288u
#define TMASK 524287u
#define TPB  256   // points per block (k2)
#define NQ   7     // levels 0..6 oct-densified

typedef __attribute__((ext_vector_type(8))) short short8;
typedef __attribute__((ext_vector_type(4))) float f32x4;

struct ResArr { float r[NLVL]; };
struct QuadInfo { int off[NQ]; int dim[NQ]; };   // off in 32B oct-entry units

__device__ __forceinline__ unsigned short f2bf(float f) {
    union { float f; unsigned u; } v; v.f = f;
    unsigned r = v.u + 0x7FFFu + ((v.u >> 16) & 1u);   // RNE
    return (unsigned short)(r >> 16);
}
__device__ __forceinline__ float blo(unsigned u) {
    union { unsigned v; float f; } x; x.v = u << 16; return x.f;
}
__device__ __forceinline__ float bhi(unsigned u) {
    union { unsigned v; float f; } x; x.v = u & 0xffff0000u; return x.f;
}
__device__ __forceinline__ unsigned packbf(float a, float b) {
    return (unsigned)f2bf(a) | ((unsigned)f2bf(b) << 16);
}

#define MFMA(a,b,c) __builtin_amdgcn_mfma_f32_16x16x32_bf16((a),(b),(c),0,0,0)

// ---------------------------------------------------------------------------
// Prep kernel: blockIdx.y = level 0..6 -> OCT arrays (32B/cell = all 8 corners
// of cell (x,y,z): lo = y/z-quad at slab x, hi = y/z-quad at slab x+1).
// l==7: block 0 packs MLP weights/biases; blocks 1..1024 repack coords->float4.
// ---------------------------------------------------------------------------
__global__ __launch_bounds__(256) void prep_k(
    const float* __restrict__ emb,
    const float* __restrict__ coords,
    float4* __restrict__ c4,
    uint4* __restrict__ oct, QuadInfo qi,
    const float* __restrict__ dw1, const float* __restrict__ db1,
    const float* __restrict__ dw2, const float* __restrict__ db2,
    const float* __restrict__ cw1, const float* __restrict__ cb1,
    const float* __restrict__ cw2, const float* __restrict__ cb2,
    const float* __restrict__ cw3, const float* __restrict__ cb3,
    const float* __restrict__ cw4, const float* __restrict__ cb4,
    unsigned short* __restrict__ wpk, float* __restrict__ bpk)
{
    const int l = blockIdx.y;
    const int tid = threadIdx.x;

    if (l == 7) {
        if (blockIdx.x == 0) {
            const int wid  = tid >> 6;
            const int lane = tid & 63;
            const int m16  = lane & 15;
            const int q    = lane >> 4;
            const unsigned char MAT[28] = {0,0,0,0, 1,1, 2,2,2,2, 3,3,3,3,3,3,3,3, 4,4,4,4,4,4,4,4, 5,5};
            const unsigned char K0 [28] = {0,0,0,0, 0,32, 0,0,0,0, 0,0,0,0,32,32,32,32, 0,0,0,0,32,32,32,32, 0,32};
            const unsigned char N0 [28] = {0,16,32,48, 0,0, 0,16,32,48, 0,16,32,48,0,16,32,48, 0,16,32,48,0,16,32,48, 0,0};
            #pragma unroll
            for (int s = 0; s < 28; ++s) {
                if ((s & 3) == wid) {
                    const int mat = MAT[s];
                    const float* src = mat==0?dw1 : mat==1?dw2 : mat==2?cw1 : mat==3?cw2 : mat==4?cw3 : cw4;
                    const int fan = (mat==1) ? 16 : (mat==5) ? 3 : 64;
                    const int k = (int)K0[s] + q*8;
                    const int n = (int)N0[s] + m16;
                    unsigned short u[8];
                    #pragma unroll
                    for (int j = 0; j < 8; ++j) {
                        float v = 0.f;
                        if (mat != 5 || n < 3) v = src[(k+j)*fan + n];
                        u[j] = f2bf(v);
                    }
                    unsigned* w32 = (unsigned*)(wpk + s*512 + lane*8);
                    w32[0] = (unsigned)u[0] | ((unsigned)u[1] << 16);
                    w32[1] = (unsigned)u[2] | ((unsigned)u[3] << 16);
                    w32[2] = (unsigned)u[4] | ((unsigned)u[5] << 16);
                    w32[3] = (unsigned)u[6] | ((unsigned)u[7] << 16);
                }
            }
            {
                int t = tid;
                if      (t <  64) bpk[t] = db1[t];
                else if (t <  80) bpk[t] = db2[t-64];
                else if (t < 144) bpk[t] = cb1[t-80];
                else if (t < 208) bpk[t] = cb2[t-144];
            }
            if (tid < 80) {
                int t = tid + 208;
                if (t < 272) bpk[t] = cb3[t-208];
                else         bpk[t] = (t-272 < 3) ? cb4[t-272] : 0.f;
            }
        } else if (blockIdx.x <= 1024) {
            const int p = (blockIdx.x - 1) * 256 + tid;
            float4 c;
            c.x = coords[3*p]; c.y = coords[3*p+1]; c.z = coords[3*p+2]; c.w = 0.f;
            c4[p] = c;
        }
        return;
    }

    const int t = blockIdx.x * 256 + tid;
    const int D = qi.dim[l];
    if (t >= D*D*D) return;
    const int DD = D*D;
    const unsigned z = (unsigned)t % (unsigned)D;
    const unsigned rem = (unsigned)t / (unsigned)D;
    const unsigned y = rem % (unsigned)D;

    const float2* __restrict__ emb2 = (const float2*)emb;
    const unsigned base = (unsigned)l * TBL;
    const unsigned x = rem / (unsigned)D;
    const unsigned hy0 = y*2654435761u, hy1 = (y+1u)*2654435761u;
    const unsigned hz0 = z*805459861u,  hz1 = (z+1u)*805459861u;

    const float2 a = emb2[base + ((x^hy0^hz0)&TMASK)];
    const float2 b = emb2[base + ((x^hy0^hz1)&TMASK)];
    const float2 c = emb2[base + ((x^hy1^hz0)&TMASK)];
    const float2 d = emb2[base + ((x^hy1^hz1)&TMASK)];

    uint4 q;
    q.x = packbf(a.x, a.y);
    q.y = packbf(b.x, b.y);
    q.z = packbf(c.x, c.y);
    q.w = packbf(d.x, d.y);

    const int e = qi.off[l] + t;
    oct[2*e] = q;                          // lo half of cell (x,y,z)
    if (t >= DD)
        oct[2*(e - DD) + 1] = q;           // hi half of cell (x-1,y,z)
}

// ---------------------------------------------------------------------------
// Kernel 1: hash-grid encode, cost-balanced XCD schedule.
// grid = 11008 blocks; xcd = b&7, s = b>>3 in [0,1376).
//  s < 1024        : hashed level (7+xcd), point chunk s
//  1024 <= s <1152 : l15 eighth
//  s >= 1152       : oct g = xcd*224+(s-1152): l=g>>8, c=g&255
// Hashed path: x-parity pairing (PRIMES[0]==1): 4x16B pair loads + 4x8B
// gathers masked to odd-x lanes = 6 req/pt avg. (unchanged this round)
// ---------------------------------------------------------------------------
__global__ __launch_bounds__(256) void hash_encode_k(
    const float4* __restrict__ c4,
    const float* __restrict__ emb,
    const uint4* __restrict__ oct,
    unsigned* __restrict__ featws,
    ResArr res, QuadInfo qi)
{
    const int tid = threadIdx.x;
    const int b   = blockIdx.x;
    const int xcd = b & 7;
    const int s   = b >> 3;

    if (s < 1152) {
        // -------- hashed path --------
        int l, p;
        if (s < 1024) {
            l = 7 + xcd;
            p = s * 256 + tid;
        } else {
            l = 15;
            p = xcd * 32768 + (s - 1024) * 256 + tid;
        }

        const float4 cc = c4[p];
        const float r = res.r[l];
        const float px = cc.x*r, py = cc.y*r, pz = cc.z*r;
        const float fpx = floorf(px), fpy = floorf(py), fpz = floorf(pz);
        const float fx = px-fpx, fy = py-fpy, fz = pz-fpz;
        const unsigned ix=(unsigned)fpx, iy=(unsigned)fpy, iz=(unsigned)fpz;
        const unsigned hy0=iy*2654435761u, hy1=(iy+1u)*2654435761u;
        const unsigned hz0=iz*805459861u,  hz1=(iz+1u)*805459861u;
        const unsigned base  = (unsigned)l * TBL;          // float2 units
        const unsigned base4 = (unsigned)l * (TBL >> 1);   // float4 units
        const float2* __restrict__ emb2 = (const float2*)emb;
        const float4* __restrict__ emb4 = (const float4*)emb;

        const unsigned m = ix ^ (ix + 1u);                 // 1 iff ix even
        const unsigned h00 = (ix^hy0^hz0) & TMASK;
        const unsigned h01 = (ix^hy0^hz1) & TMASK;
        const unsigned h10 = (ix^hy1^hz0) & TMASK;
        const unsigned h11 = (ix^hy1^hz1) & TMASK;

        // pair loads: float4 at h>>1 = entries {h&~1, h|1}
        const float4 p00 = emb4[base4 + (h00 >> 1)];
        const float4 p01 = emb4[base4 + (h01 >> 1)];
        const float4 p10 = emb4[base4 + (h10 >> 1)];
        const float4 p11 = emb4[base4 + (h11 >> 1)];

        // x0 corner = half selected by h&1; x1 corner = other half (iff m==1)
        float2 f000, f001, f010, f011, f100, f101, f110, f111;
        f000.x = (h00&1) ? p00.z : p00.x;  f000.y = (h00&1) ? p00.w : p00.y;
        f001.x = (h01&1) ? p01.z : p01.x;  f001.y = (h01&1) ? p01.w : p01.y;
        f010.x = (h10&1) ? p10.z : p10.x;  f010.y = (h10&1) ? p10.w : p10.y;
        f011.x = (h11&1) ? p11.z : p11.x;  f011.y = (h11&1) ? p11.w : p11.y;
        f100.x = (h00&1) ? p00.x : p00.z;  f100.y = (h00&1) ? p00.y : p00.w;
        f101.x = (h01&1) ? p01.x : p01.z;  f101.y = (h01&1) ? p01.y : p01.w;
        f110.x = (h10&1) ? p10.x : p10.z;  f110.y = (h10&1) ? p10.y : p10.w;
        f111.x = (h11&1) ? p11.x : p11.z;  f111.y = (h11&1) ? p11.y : p11.w;

        if (m != 1u) {
            // odd-x lanes: true x1 corners are h^m, not in the pair
            f100 = emb2[base + ((h00 ^ m) & TMASK)];
            f101 = emb2[base + ((h01 ^ m) & TMASK)];
            f110 = emb2[base + ((h10 ^ m) & TMASK)];
            f111 = emb2[base + ((h11 ^ m) & TMASK)];
        }

        const float wx0=1.f-fx, wy0=1.f-fy, wz0=1.f-fz;
        float o0, o1;
        o0 = wx0*wy0*wz0*f000.x;                 o1 = wx0*wy0*wz0*f000.y;
        o0 = fmaf(wx0*wy0*fz,  f001.x, o0);      o1 = fmaf(wx0*wy0*fz,  f001.y, o1);
        o0 = fmaf(wx0*fy*wz0,  f010.x, o0);      o1 = fmaf(wx0*fy*wz0,  f010.y, o1);
        o0 = fmaf(wx0*fy*fz,   f011.x, o0);      o1 = fmaf(wx0*fy*fz,   f011.y, o1);
        o0 = fmaf(fx*wy0*wz0,  f100.x, o0);      o1 = fmaf(fx*wy0*wz0,  f100.y, o1);
        o0 = fmaf(fx*wy0*fz,   f101.x, o0);      o1 = fmaf(fx*wy0*fz,   f101.y, o1);
        o0 = fmaf(fx*fy*wz0,   f110.x, o0);      o1 = fmaf(fx*fy*wz0,   f110.y, o1);
        o0 = fmaf(fx*fy*fz,    f111.x, o0);      o1 = fmaf(fx*fy*fz,    f111.y, o1);

        featws[(size_t)l * NPTS + p] = packbf(o0, o1);
    } else {
        // -------- oct path: 4 points/thread, 1 line/point --------
        const int g  = xcd * 224 + (s - 1152);    // 0..1791
        const int l  = g >> 8;                    // 0..6
        const int c  = g & 255;
        const int D  = qi.dim[l];
        const int off = qi.off[l];
        const float r = res.r[l];

        int   pidx[4];
        uint4 qA[4], qB[4];
        float fxa[4], fya[4], fza[4];
        #pragma unroll
        for (int k = 0; k < 4; ++k) {
            const int p = c*1024 + k*256 + tid;
            pidx[k] = p;
            const float4 cc = c4[p];
            const float px = cc.x*r, py = cc.y*r, pz = cc.z*r;
            const float fpx = floorf(px), fpy = floorf(py), fpz = floorf(pz);
            fxa[k] = px-fpx; fya[k] = py-fpy; fza[k] = pz-fpz;
            const int ix=(int)fpx, iy=(int)fpy, iz=(int)fpz;
            const int v0 = off + (ix*D + iy)*D + iz;
            qA[k] = oct[2*v0];
            qB[k] = oct[2*v0 + 1];
        }
        #pragma unroll
        for (int k = 0; k < 4; ++k) {
            const float fx = fxa[k], fy = fya[k], fz = fza[k];
            const float wx0=1.f-fx, wy0=1.f-fy, wz0=1.f-fz;
            const float w000=wx0*wy0*wz0, w001=wx0*wy0*fz;
            const float w010=wx0*fy*wz0,  w011=wx0*fy*fz;
            const float w100=fx*wy0*wz0,  w101=fx*wy0*fz;
            const float w110=fx*fy*wz0,   w111=fx*fy*fz;
            float o0, o1;
            o0 = w000*blo(qA[k].x);              o1 = w000*bhi(qA[k].x);
            o0 = fmaf(w001, blo(qA[k].y), o0);   o1 = fmaf(w001, bhi(qA[k].y), o1);
            o0 = fmaf(w010, blo(qA[k].z), o0);   o1 = fmaf(w010, bhi(qA[k].z), o1);
            o0 = fmaf(w011, blo(qA[k].w), o0);   o1 = fmaf(w011, bhi(qA[k].w), o1);
            o0 = fmaf(w100, blo(qB[k].x), o0);   o1 = fmaf(w100, bhi(qB[k].x), o1);
            o0 = fmaf(w101, blo(qB[k].y), o0);   o1 = fmaf(w101, bhi(qB[k].y), o1);
            o0 = fmaf(w110, blo(qB[k].z), o0);   o1 = fmaf(w110, bhi(qB[k].z), o1);
            o0 = fmaf(w111, blo(qB[k].w), o0);   o1 = fmaf(w111, bhi(qB[k].w), o1);
            featws[(size_t)l * NPTS + pidx[k]] = packbf(o0, o1);
        }
    }
}

// ---------------------------------------------------------------------------
// Kernel 2: MFMA MLP chain. R3: featL staging dropped -> A-frags loaded
// directly from featws (4 dwords/lane, L2-hot). LDS 39KB -> 4 blocks/CU
// (was 2), __launch_bounds__(256,4) caps VGPR at 128, unroll 1 on the iter
// loop keeps pressure down. No syncthreads in the iter loop (actL per-wave).
// ---------------------------------------------------------------------------
__global__ __launch_bounds__(256, 4) void mlp_mfma_k(
    const unsigned* __restrict__ featws,
    const unsigned short* __restrict__ wpk,
    const float* __restrict__ bpk,
    const float* __restrict__ dirs,
    float* __restrict__ out)
{
    const int tid  = threadIdx.x;
    const int wid  = tid >> 6;
    const int lane = tid & 63;
    const int m16  = lane & 15;
    const int q    = lane >> 4;

    __shared__ __align__(16) unsigned short wlds[28 * 512];
    __shared__ float blds[288];
    __shared__ __align__(16) unsigned short actL[4 * 16 * 72]; // per-wave [16][64+8] bf16

    {
        uint4* dst = (uint4*)wlds;
        const uint4* srcv = (const uint4*)wpk;   // 1792 uint4
        #pragma unroll
        for (int j = 0; j < 7; ++j) dst[j*256 + tid] = srcv[j*256 + tid];
        if (tid < 256) blds[tid] = bpk[tid];             // biases 0..255
        if (tid < 32)  blds[256 + tid] = bpk[256 + tid]; // 256..287 (cb3 tail + cb4)
    }
    __syncthreads();

    const int pbase = blockIdx.x * TPB;

    unsigned short* aw = actL + wid*1152;     // 16 x 72
    const short8* wfr = (const short8*)wlds;  // B(s) = wfr[s*64 + lane]

    #pragma unroll 1
    for (int iter = 0; iter < 4; ++iter) {
        const int tile = wid + 4*iter;
        const int loc0 = tile*16;
        const int p0g  = pbase + loc0;

        // ---- A-frag for density L1: levels q*4..q*4+3 of point p0g+m16 ----
        union { unsigned u[4]; short8 s; } af;
        #pragma unroll
        for (int j = 0; j < 4; ++j)
            af.u[j] = featws[(size_t)(q*4 + j) * NPTS + p0g + m16];
        const short8 a0 = af.s;

        // ---- density L1: feat(32) -> 64, relu ----
        f32x4 acc[4];
        #pragma unroll
        for (int nc = 0; nc < 4; ++nc) {
            const float b = blds[nc*16 + m16];
            acc[nc] = (f32x4){b,b,b,b};
            acc[nc] = MFMA(a0, wfr[nc*64 + lane], acc[nc]);
        }
        #pragma unroll
        for (int nc = 0; nc < 4; ++nc)
            #pragma unroll
            for (int r = 0; r < 4; ++r)
                aw[(q*4+r)*72 + nc*16 + m16] = f2bf(fmaxf(acc[nc][r], 0.f));

        // ---- density L2: 64 -> 16 (no act) ----
        short8 ad0 = *(const short8*)(aw + m16*72 + q*8);
        short8 ad1 = *(const short8*)(aw + m16*72 + 32 + q*8);
        f32x4 dob;
        { const float b = blds[64 + m16]; dob = (f32x4){b,b,b,b}; }
        dob = MFMA(ad0, wfr[4*64 + lane], dob);
        dob = MFMA(ad1, wfr[5*64 + lane], dob);

        if (m16 == 0) {
            #pragma unroll
            for (int r = 0; r < 4; ++r) out[p0g + q*4 + r] = expf(dob[r]);
        }

        // ---- build inp = [SH(16) | dob(16)] ----
        #pragma unroll
        for (int r = 0; r < 4; ++r)
            aw[(q*4+r)*72 + 16 + m16] = f2bf(dob[r]);
        {
            const int pg = p0g + m16;
            const float dx0 = dirs[3*pg], dy0 = dirs[3*pg+1], dz0 = dirs[3*pg+2];
            const float inv = 1.f / sqrtf(dx0*dx0 + dy0*dy0 + dz0*dz0);
            float x = dx0*inv, y = dy0*inv, z = dz0*inv;
            x = ((x+1.f)*0.5f)*2.f - 1.f;
            y = ((y+1.f)*0.5f)*2.f - 1.f;
            z = ((z+1.f)*0.5f)*2.f - 1.f;
            float s0, s1, s2, s3;
            switch (q) {
            case 0: s0 = 0.28209479177387814f;
                    s1 = -0.48860251190291987f*y;
                    s2 =  0.48860251190291987f*z;
                    s3 = -0.48860251190291987f*x; break;
            case 1: s0 =  1.0925484305920792f*x*y;
                    s1 = -1.0925484305920792f*y*z;
                    s2 =  0.94617469575756f*z*z - 0.31539156525252f;
                    s3 = -1.0925484305920792f*x*z; break;
            case 2: s0 =  0.5462742152960396f*(x*x - y*y);
                    s1 =  0.5900435899266435f*y*(-3.f*x*x + y*y);
                    s2 =  2.890611442640554f*x*y*z;
                    s3 =  0.4570457994644657f*y*(1.f - 5.f*z*z); break;
            default:s0 =  0.3731763325901154f*z*(5.f*z*z - 3.f);
                    s1 =  0.4570457994644657f*x*(1.f - 5.f*z*z);
                    s2 =  1.445305721320277f*z*(x*x - y*y);
                    s3 =  0.5900435899266435f*x*(x*x - 3.f*y*y); break;
            }
            unsigned* ip = (unsigned*)(aw + m16*72 + q*4);
            ip[0] = packbf(s0, s1);
            ip[1] = packbf(s2, s3);
        }

        // ---- color L1: inp(32) -> 64, relu ----
        short8 ac0 = *(const short8*)(aw + m16*72 + q*8);
        #pragma unroll
        for (int nc = 0; nc < 4; ++nc) {
            const float b = blds[80 + nc*16 + m16];
            acc[nc] = (f32x4){b,b,b,b};
            acc[nc] = MFMA(ac0, wfr[(6+nc)*64 + lane], acc[nc]);
        }
        #pragma unroll
        for (int nc = 0; nc < 4; ++nc)
            #pragma unroll
            for (int r = 0; r < 4; ++r)
                aw[(q*4+r)*72 + nc*16 + m16] = f2bf(fmaxf(acc[nc][r], 0.f));

        // ---- color L2: 64 -> 64, relu ----
        short8 a20 = *(const short8*)(aw + m16*72 + q*8);
        short8 a21 = *(const short8*)(aw + m16*72 + 32 + q*8);
        #pragma unroll
        for (int nc = 0; nc < 4; ++nc) {
            const float b = blds[144 + nc*16 + m16];
            acc[nc] = (f32x4){b,b,b,b};
            acc[nc] = MFMA(a20, wfr[(10+nc)*64 + lane], acc[nc]);
            acc[nc] = MFMA(a21, wfr[(14+nc)*64 + lane], acc[nc]);
        }
        #pragma unroll
        for (int nc = 0; nc < 4; ++nc)
            #pragma unroll
            for (int r = 0; r < 4; ++r)
                aw[(q*4+r)*72 + nc*16 + m16] = f2bf(fmaxf(acc[nc][r], 0.f));

        // ---- color L3: 64 -> 64, relu ----
        short8 a30 = *(const short8*)(aw + m16*72 + q*8);
        short8 a31 = *(const short8*)(aw + m16*72 + 32 + q*8);
        #pragma unroll
        for (int nc = 0; nc < 4; ++nc) {
            const float b = blds[208 + nc*16 + m16];
            acc[nc] = (f32x4){b,b,b,b};
            acc[nc] = MFMA(a30, wfr[(18+nc)*64 + lane], acc[nc]);
            acc[nc] = MFMA(a31, wfr[(22+nc)*64 + lane], acc[nc]);
        }
        #pragma unroll
        for (int nc = 0; nc < 4; ++nc)
            #pragma unroll
            for (int r = 0; r < 4; ++r)
                aw[(q*4+r)*72 + nc*16 + m16] = f2bf(fmaxf(acc[nc][r], 0.f));

        // ---- color L4: 64 -> 3 (padded to 16), sigmoid ----
        short8 a40 = *(const short8*)(aw + m16*72 + q*8);
        short8 a41 = *(const short8*)(aw + m16*72 + 32 + q*8);
        f32x4 c4v;
        { const float b = blds[272 + m16]; c4v = (f32x4){b,b,b,b}; }
        c4v = MFMA(a40, wfr[26*64 + lane], c4v);
        c4v = MFMA(a41, wfr[27*64 + lane], c4v);
        if (m16 < 3) {
            #pragma unroll
            for (int r = 0; r < 4; ++r)
                out[NPTS + 3*(p0g + q*4 + r) + m16] = 1.f / (1.f + expf(-c4v[r]));
        }
    }
}

extern "C" void kernel_launch(void* const* d_in, const int* in_sizes, int n_in,
                              void* d_out, int out_size, void* d_ws, size_t ws_size,
                              hipStream_t stream)
{
    // RES must bit-match numpy: floor(16 * b**l) in f64, b = exp((ln512-ln16)/15).
    ResArr res;
    const double b = exp((log(512.0) - log(16.0)) / 15.0);
    for (int l = 0; l < NLVL; ++l)
        res.r[l] = (float)floor(16.0 * pow(b, (double)l));

    // oct arrays for levels 0..6: dim = res+1
    QuadInfo qi;
    int off = 0, maxn = 0;
    for (int l = 0; l < NQ; ++l) {
        const int D = (int)res.r[l] + 1;
        qi.dim[l] = D;
        qi.off[l] = off;
        off += D*D*D;
        if (D*D*D > maxn) maxn = D*D*D;
    }

    // ws: featws 16.8MB | oct (543,884*32B = 17.4MB) | c4 4MB | wpk 28KB | bpk 1.2KB
    unsigned*       featws = (unsigned*)d_ws;
    uint4*          oct    = (uint4*)((char*)d_ws + (size_t)NLVL * NPTS * 4);
    float4*         c4     = (float4*)((char*)oct + (size_t)off * 32);
    unsigned short* wpk    = (unsigned short*)((char*)c4 + (size_t)NPTS * 16);
    float*          bpk    = (float*)((char*)wpk + 28 * 512 * 2);

    prep_k<<<dim3((maxn + 255)/256, 8), 256, 0, stream>>>(
        (const float*)d_in[2],   // embeddings
        (const float*)d_in[0],   // coords
        c4, oct, qi,
        (const float*)d_in[3],  (const float*)d_in[4],
        (const float*)d_in[5],  (const float*)d_in[6],
        (const float*)d_in[7],  (const float*)d_in[8],
        (const float*)d_in[9],  (const float*)d_in[10],
        (const float*)d_in[11], (const float*)d_in[12],
        (const float*)d_in[13], (const float*)d_in[14],
        wpk, bpk);

    hash_encode_k<<<11008, 256, 0, stream>>>(
        c4,
        (const float*)d_in[2],   // embeddings
        oct, featws, res, qi);

    mlp_mfma_k<<<NPTS/TPB, 256, 0, stream>>>(
        featws, wpk, bpk,
        (const float*)d_in[1],   // directions
        (float*)d_out);
}

// Round 4
// 229.556 us; speedup vs baseline: 1.1274x; 1.0435x over previous
//
#include <hip/hip_runtime.h>
#include <cmath>

#define NPTS 262144
#define NLVL 16
#define TBL  524288u
#define TMASK 524287u
#define TPB  256   // points per block (k2)
#define NQ   7     // levels 0..6 oct-densified

typedef __attribute__((ext_vector_type(8))) short short8;
typedef __attribute__((ext_vector_type(4))) float f32x4;

struct ResArr { float r[NLVL]; };
struct QuadInfo { int off[NQ]; int dim[NQ]; };   // off in 32B oct-entry units

__device__ __forceinline__ unsigned short f2bf(float f) {
    union { float f; unsigned u; } v; v.f = f;
    unsigned r = v.u + 0x7FFFu + ((v.u >> 16) & 1u);   // RNE
    return (unsigned short)(r >> 16);
}
__device__ __forceinline__ float blo(unsigned u) {
    union { unsigned v; float f; } x; x.v = u << 16; return x.f;
}
__device__ __forceinline__ float bhi(unsigned u) {
    union { unsigned v; float f; } x; x.v = u & 0xffff0000u; return x.f;
}
__device__ __forceinline__ unsigned packbf(float a, float b) {
    return (unsigned)f2bf(a) | ((unsigned)f2bf(b) << 16);
}

#define MFMA(a,b,c) __builtin_amdgcn_mfma_f32_16x16x32_bf16((a),(b),(c),0,0,0)

// ---------------------------------------------------------------------------
// Kernel 1 (fused): hash-grid encode for levels 7..15 + oct BUILD for levels
// 0..6 + weight/bias pack, all in one request stream.
// grid = smax*8 blocks; xcd = b&7, s = b>>3.
//  s < 1024          : hashed level (7+xcd), point chunk s
//  1024 <= s < 1152  : l15 eighth
//  s >= 1152         : tail rank = xcd*tailn + (s-1152):
//                       rank < ncb  -> oct build, cells rank*256+tid
//                       rank == ncb -> weight/bias pack
// Build work is independent of hashed work -> overlaps in the same dispatch
// instead of a serialized prep kernel.
// ---------------------------------------------------------------------------
__global__ __launch_bounds__(256) void fused_encode_k(
    const float* __restrict__ coords,
    const float* __restrict__ emb,
    uint4* __restrict__ oct,
    unsigned* __restrict__ featws,
    const float* __restrict__ dw1, const float* __restrict__ db1,
    const float* __restrict__ dw2, const float* __restrict__ db2,
    const float* __restrict__ cw1, const float* __restrict__ cb1,
    const float* __restrict__ cw2, const float* __restrict__ cb2,
    const float* __restrict__ cw3, const float* __restrict__ cb3,
    const float* __restrict__ cw4, const float* __restrict__ cb4,
    unsigned short* __restrict__ wpk, float* __restrict__ bpk,
    ResArr res, QuadInfo qi, int ncell, int ncb, int tailn)
{
    const int tid = threadIdx.x;
    const int b   = blockIdx.x;
    const int xcd = b & 7;
    const int s   = b >> 3;

    if (s < 1152) {
        // -------- hashed path (levels 7..15), x-parity pairing --------
        int l, p;
        if (s < 1024) {
            l = 7 + xcd;
            p = s * 256 + tid;
        } else {
            l = 15;
            p = xcd * 32768 + (s - 1024) * 256 + tid;
        }

        const float cx = coords[3*p], cy = coords[3*p+1], cz = coords[3*p+2];
        const float r = res.r[l];
        const float px = cx*r, py = cy*r, pz = cz*r;
        const float fpx = floorf(px), fpy = floorf(py), fpz = floorf(pz);
        const float fx = px-fpx, fy = py-fpy, fz = pz-fpz;
        const unsigned ix=(unsigned)fpx, iy=(unsigned)fpy, iz=(unsigned)fpz;
        const unsigned hy0=iy*2654435761u, hy1=(iy+1u)*2654435761u;
        const unsigned hz0=iz*805459861u,  hz1=(iz+1u)*805459861u;
        const unsigned base  = (unsigned)l * TBL;          // float2 units
        const unsigned base4 = (unsigned)l * (TBL >> 1);   // float4 units
        const float2* __restrict__ emb2 = (const float2*)emb;
        const float4* __restrict__ emb4 = (const float4*)emb;

        const unsigned m = ix ^ (ix + 1u);                 // 1 iff ix even
        const unsigned h00 = (ix^hy0^hz0) & TMASK;
        const unsigned h01 = (ix^hy0^hz1) & TMASK;
        const unsigned h10 = (ix^hy1^hz0) & TMASK;
        const unsigned h11 = (ix^hy1^hz1) & TMASK;

        // pair loads: float4 at h>>1 = entries {h&~1, h|1}
        const float4 p00 = emb4[base4 + (h00 >> 1)];
        const float4 p01 = emb4[base4 + (h01 >> 1)];
        const float4 p10 = emb4[base4 + (h10 >> 1)];
        const float4 p11 = emb4[base4 + (h11 >> 1)];

        // x0 corner = half selected by h&1; x1 corner = other half (iff m==1)
        float2 f000, f001, f010, f011, f100, f101, f110, f111;
        f000.x = (h00&1) ? p00.z : p00.x;  f000.y = (h00&1) ? p00.w : p00.y;
        f001.x = (h01&1) ? p01.z : p01.x;  f001.y = (h01&1) ? p01.w : p01.y;
        f010.x = (h10&1) ? p10.z : p10.x;  f010.y = (h10&1) ? p10.w : p10.y;
        f011.x = (h11&1) ? p11.z : p11.x;  f011.y = (h11&1) ? p11.w : p11.y;
        f100.x = (h00&1) ? p00.x : p00.z;  f100.y = (h00&1) ? p00.y : p00.w;
        f101.x = (h01&1) ? p01.x : p01.z;  f101.y = (h01&1) ? p01.y : p01.w;
        f110.x = (h10&1) ? p10.x : p10.z;  f110.y = (h10&1) ? p10.y : p10.w;
        f111.x = (h11&1) ? p11.x : p11.z;  f111.y = (h11&1) ? p11.y : p11.w;

        if (m != 1u) {
            // odd-x lanes: true x1 corners are h^m, not in the pair
            f100 = emb2[base + ((h00 ^ m) & TMASK)];
            f101 = emb2[base + ((h01 ^ m) & TMASK)];
            f110 = emb2[base + ((h10 ^ m) & TMASK)];
            f111 = emb2[base + ((h11 ^ m) & TMASK)];
        }

        const float wx0=1.f-fx, wy0=1.f-fy, wz0=1.f-fz;
        float o0, o1;
        o0 = wx0*wy0*wz0*f000.x;                 o1 = wx0*wy0*wz0*f000.y;
        o0 = fmaf(wx0*wy0*fz,  f001.x, o0);      o1 = fmaf(wx0*wy0*fz,  f001.y, o1);
        o0 = fmaf(wx0*fy*wz0,  f010.x, o0);      o1 = fmaf(wx0*fy*wz0,  f010.y, o1);
        o0 = fmaf(wx0*fy*fz,   f011.x, o0);      o1 = fmaf(wx0*fy*fz,   f011.y, o1);
        o0 = fmaf(fx*wy0*wz0,  f100.x, o0);      o1 = fmaf(fx*wy0*wz0,  f100.y, o1);
        o0 = fmaf(fx*wy0*fz,   f101.x, o0);      o1 = fmaf(fx*wy0*fz,   f101.y, o1);
        o0 = fmaf(fx*fy*wz0,   f110.x, o0);      o1 = fmaf(fx*fy*wz0,   f110.y, o1);
        o0 = fmaf(fx*fy*fz,    f111.x, o0);      o1 = fmaf(fx*fy*fz,    f111.y, o1);

        featws[(size_t)l * NPTS + p] = packbf(o0, o1);
    } else {
        const int rank = xcd * tailn + (s - 1152);
        if (rank < ncb) {
            // -------- oct build (was prep_k levels 0..6) --------
            const int gcell = rank * 256 + tid;
            if (gcell >= ncell) return;

            int l = 0;
            #pragma unroll
            for (int j = 1; j < NQ; ++j) if (gcell >= qi.off[j]) l = j;
            const int off = qi.off[l];
            const int D   = qi.dim[l];
            const int t   = gcell - off;
            const int DD  = D*D;

            const unsigned z = (unsigned)t % (unsigned)D;
            const unsigned rem = (unsigned)t / (unsigned)D;
            const unsigned y = rem % (unsigned)D;
            const unsigned x = rem / (unsigned)D;

            const float2* __restrict__ emb2 = (const float2*)emb;
            const unsigned base = (unsigned)l * TBL;
            const unsigned hy0 = y*2654435761u, hy1 = (y+1u)*2654435761u;
            const unsigned hz0 = z*805459861u,  hz1 = (z+1u)*805459861u;

            const float2 a = emb2[base + ((x^hy0^hz0)&TMASK)];
            const float2 bb= emb2[base + ((x^hy0^hz1)&TMASK)];
            const float2 c = emb2[base + ((x^hy1^hz0)&TMASK)];
            const float2 d = emb2[base + ((x^hy1^hz1)&TMASK)];

            uint4 q;
            q.x = packbf(a.x, a.y);
            q.y = packbf(bb.x, bb.y);
            q.z = packbf(c.x, c.y);
            q.w = packbf(d.x, d.y);

            const int e = off + t;
            oct[2*e] = q;                          // lo half of cell (x,y,z)
            if (t >= DD)
                oct[2*(e - DD) + 1] = q;           // hi half of cell (x-1,y,z)
        } else if (rank == ncb) {
            // -------- weight/bias pack (was prep_k l==7 block 0) --------
            const int wid  = tid >> 6;
            const int lane = tid & 63;
            const int m16  = lane & 15;
            const int q    = lane >> 4;
            const unsigned char MAT[28] = {0,0,0,0, 1,1, 2,2,2,2, 3,3,3,3,3,3,3,3, 4,4,4,4,4,4,4,4, 5,5};
            const unsigned char K0 [28] = {0,0,0,0, 0,32, 0,0,0,0, 0,0,0,0,32,32,32,32, 0,0,0,0,32,32,32,32, 0,32};
            const unsigned char N0 [28] = {0,16,32,48, 0,0, 0,16,32,48, 0,16,32,48,0,16,32,48, 0,16,32,48,0,16,32,48, 0,0};
            #pragma unroll
            for (int s2 = 0; s2 < 28; ++s2) {
                if ((s2 & 3) == wid) {
                    const int mat = MAT[s2];
                    const float* src = mat==0?dw1 : mat==1?dw2 : mat==2?cw1 : mat==3?cw2 : mat==4?cw3 : cw4;
                    const int fan = (mat==1) ? 16 : (mat==5) ? 3 : 64;
                    const int k = (int)K0[s2] + q*8;
                    const int n = (int)N0[s2] + m16;
                    unsigned short u[8];
                    #pragma unroll
                    for (int j = 0; j < 8; ++j) {
                        float v = 0.f;
                        if (mat != 5 || n < 3) v = src[(k+j)*fan + n];
                        u[j] = f2bf(v);
                    }
                    unsigned* w32 = (unsigned*)(wpk + s2*512 + lane*8);
                    w32[0] = (unsigned)u[0] | ((unsigned)u[1] << 16);
                    w32[1] = (unsigned)u[2] | ((unsigned)u[3] << 16);
                    w32[2] = (unsigned)u[4] | ((unsigned)u[5] << 16);
                    w32[3] = (unsigned)u[6] | ((unsigned)u[7] << 16);
                }
            }
            {
                int t = tid;
                if      (t <  64) bpk[t] = db1[t];
                else if (t <  80) bpk[t] = db2[t-64];
                else if (t < 144) bpk[t] = cb1[t-80];
                else if (t < 208) bpk[t] = cb2[t-144];
            }
            if (tid < 80) {
                int t = tid + 208;
                if (t < 272) bpk[t] = cb3[t-208];
                else         bpk[t] = (t-272 < 3) ? cb4[t-272] : 0.f;
            }
        }
    }
}

// ---------------------------------------------------------------------------
// Kernel 2: oct consume (levels 0..6) + MFMA MLP chain. Each block first
// computes its 256 points' levels 0..6 from oct into LDS (7 line-req/pt,
// hides under the MFMA latency chain), then runs the MLP. A-frags mix
// featO (LDS, levels 0..6) and featws (global, levels 7..15).
// LDS ~47KB -> 3 blocks/CU.
// ---------------------------------------------------------------------------
__global__ __launch_bounds__(256, 3) void mlp_mfma_k(
    const unsigned* __restrict__ featws,
    const uint4* __restrict__ oct,
    const float* __restrict__ coords,
    const unsigned short* __restrict__ wpk,
    const float* __restrict__ bpk,
    const float* __restrict__ dirs,
    float* __restrict__ out,
    ResArr res, QuadInfo qi)
{
    const int tid  = threadIdx.x;
    const int wid  = tid >> 6;
    const int lane = tid & 63;
    const int m16  = lane & 15;
    const int q    = lane >> 4;

    __shared__ __align__(16) unsigned short wlds[28 * 512];
    __shared__ float blds[288];
    __shared__ __align__(16) unsigned short actL[4 * 16 * 72]; // per-wave [16][64+8] bf16
    __shared__ unsigned featO[256 * 8];                        // [pt][lvl 0..6 + pad]

    {
        uint4* dst = (uint4*)wlds;
        const uint4* srcv = (const uint4*)wpk;   // 1792 uint4
        #pragma unroll
        for (int j = 0; j < 7; ++j) dst[j*256 + tid] = srcv[j*256 + tid];
        if (tid < 256) blds[tid] = bpk[tid];             // biases 0..255
        if (tid < 32)  blds[256 + tid] = bpk[256 + tid]; // 256..287 (cb3 tail + cb4)
    }

    const int pbase = blockIdx.x * TPB;

    // ---- oct consume: levels 0..6 for point pbase+tid ----
    {
        const int p = pbase + tid;
        const float cx = coords[3*p], cy = coords[3*p+1], cz = coords[3*p+2];
        #pragma unroll
        for (int l = 0; l < NQ; ++l) {
            const float r = res.r[l];
            const float px = cx*r, py = cy*r, pz = cz*r;
            const float fpx = floorf(px), fpy = floorf(py), fpz = floorf(pz);
            const float fx = px-fpx, fy = py-fpy, fz = pz-fpz;
            const int ix=(int)fpx, iy=(int)fpy, iz=(int)fpz;
            const int D = qi.dim[l];
            const int v0 = qi.off[l] + (ix*D + iy)*D + iz;
            const uint4 qA = oct[2*v0];
            const uint4 qB = oct[2*v0 + 1];
            const float wx0=1.f-fx, wy0=1.f-fy, wz0=1.f-fz;
            const float w000=wx0*wy0*wz0, w001=wx0*wy0*fz;
            const float w010=wx0*fy*wz0,  w011=wx0*fy*fz;
            const float w100=fx*wy0*wz0,  w101=fx*wy0*fz;
            const float w110=fx*fy*wz0,   w111=fx*fy*fz;
            float o0, o1;
            o0 = w000*blo(qA.x);              o1 = w000*bhi(qA.x);
            o0 = fmaf(w001, blo(qA.y), o0);   o1 = fmaf(w001, bhi(qA.y), o1);
            o0 = fmaf(w010, blo(qA.z), o0);   o1 = fmaf(w010, bhi(qA.z), o1);
            o0 = fmaf(w011, blo(qA.w), o0);   o1 = fmaf(w011, bhi(qA.w), o1);
            o0 = fmaf(w100, blo(qB.x), o0);   o1 = fmaf(w100, bhi(qB.x), o1);
            o0 = fmaf(w101, blo(qB.y), o0);   o1 = fmaf(w101, bhi(qB.y), o1);
            o0 = fmaf(w110, blo(qB.z), o0);   o1 = fmaf(w110, bhi(qB.z), o1);
            o0 = fmaf(w111, blo(qB.w), o0);   o1 = fmaf(w111, bhi(qB.w), o1);
            featO[tid*8 + l] = packbf(o0, o1);
        }
    }
    __syncthreads();

    unsigned short* aw = actL + wid*1152;     // 16 x 72
    const short8* wfr = (const short8*)wlds;  // B(s) = wfr[s*64 + lane]

    #pragma unroll 1
    for (int iter = 0; iter < 4; ++iter) {
        const int tile = wid + 4*iter;
        const int loc0 = tile*16;
        const int p0g  = pbase + loc0;

        // ---- A-frag for density L1: levels q*4..q*4+3 of point p0g+m16 ----
        union { unsigned u[4]; short8 s; } af;
        #pragma unroll
        for (int j = 0; j < 4; ++j) {
            const int lvl = q*4 + j;
            af.u[j] = (lvl < NQ) ? featO[(loc0+m16)*8 + lvl]
                                 : featws[(size_t)lvl * NPTS + p0g + m16];
        }
        const short8 a0 = af.s;

        // ---- density L1: feat(32) -> 64, relu ----
        f32x4 acc[4];
        #pragma unroll
        for (int nc = 0; nc < 4; ++nc) {
            const float b = blds[nc*16 + m16];
            acc[nc] = (f32x4){b,b,b,b};
            acc[nc] = MFMA(a0, wfr[nc*64 + lane], acc[nc]);
        }
        #pragma unroll
        for (int nc = 0; nc < 4; ++nc)
            #pragma unroll
            for (int r = 0; r < 4; ++r)
                aw[(q*4+r)*72 + nc*16 + m16] = f2bf(fmaxf(acc[nc][r], 0.f));

        // ---- density L2: 64 -> 16 (no act) ----
        short8 ad0 = *(const short8*)(aw + m16*72 + q*8);
        short8 ad1 = *(const short8*)(aw + m16*72 + 32 + q*8);
        f32x4 dob;
        { const float b = blds[64 + m16]; dob = (f32x4){b,b,b,b}; }
        dob = MFMA(ad0, wfr[4*64 + lane], dob);
        dob = MFMA(ad1, wfr[5*64 + lane], dob);

        if (m16 == 0) {
            #pragma unroll
            for (int r = 0; r < 4; ++r) out[p0g + q*4 + r] = expf(dob[r]);
        }

        // ---- build inp = [SH(16) | dob(16)] ----
        #pragma unroll
        for (int r = 0; r < 4; ++r)
            aw[(q*4+r)*72 + 16 + m16] = f2bf(dob[r]);
        {
            const int pg = p0g + m16;
            const float dx0 = dirs[3*pg], dy0 = dirs[3*pg+1], dz0 = dirs[3*pg+2];
            const float inv = 1.f / sqrtf(dx0*dx0 + dy0*dy0 + dz0*dz0);
            float x = dx0*inv, y = dy0*inv, z = dz0*inv;
            x = ((x+1.f)*0.5f)*2.f - 1.f;
            y = ((y+1.f)*0.5f)*2.f - 1.f;
            z = ((z+1.f)*0.5f)*2.f - 1.f;
            float s0, s1, s2, s3;
            switch (q) {
            case 0: s0 = 0.28209479177387814f;
                    s1 = -0.48860251190291987f*y;
                    s2 =  0.48860251190291987f*z;
                    s3 = -0.48860251190291987f*x; break;
            case 1: s0 =  1.0925484305920792f*x*y;
                    s1 = -1.0925484305920792f*y*z;
                    s2 =  0.94617469575756f*z*z - 0.31539156525252f;
                    s3 = -1.0925484305920792f*x*z; break;
            case 2: s0 =  0.5462742152960396f*(x*x - y*y);
                    s1 =  0.5900435899266435f*y*(-3.f*x*x + y*y);
                    s2 =  2.890611442640554f*x*y*z;
                    s3 =  0.4570457994644657f*y*(1.f - 5.f*z*z); break;
            default:s0 =  0.3731763325901154f*z*(5.f*z*z - 3.f);
                    s1 =  0.4570457994644657f*x*(1.f - 5.f*z*z);
                    s2 =  1.445305721320277f*z*(x*x - y*y);
                    s3 =  0.5900435899266435f*x*(x*x - 3.f*y*y); break;
            }
            unsigned* ip = (unsigned*)(aw + m16*72 + q*4);
            ip[0] = packbf(s0, s1);
            ip[1] = packbf(s2, s3);
        }

        // ---- color L1: inp(32) -> 64, relu ----
        short8 ac0 = *(const short8*)(aw + m16*72 + q*8);
        #pragma unroll
        for (int nc = 0; nc < 4; ++nc) {
            const float b = blds[80 + nc*16 + m16];
            acc[nc] = (f32x4){b,b,b,b};
            acc[nc] = MFMA(ac0, wfr[(6+nc)*64 + lane], acc[nc]);
        }
        #pragma unroll
        for (int nc = 0; nc < 4; ++nc)
            #pragma unroll
            for (int r = 0; r < 4; ++r)
                aw[(q*4+r)*72 + nc*16 + m16] = f2bf(fmaxf(acc[nc][r], 0.f));

        // ---- color L2: 64 -> 64, relu ----
        short8 a20 = *(const short8*)(aw + m16*72 + q*8);
        short8 a21 = *(const short8*)(aw + m16*72 + 32 + q*8);
        #pragma unroll
        for (int nc = 0; nc < 4; ++nc) {
            const float b = blds[144 + nc*16 + m16];
            acc[nc] = (f32x4){b,b,b,b};
            acc[nc] = MFMA(a20, wfr[(10+nc)*64 + lane], acc[nc]);
            acc[nc] = MFMA(a21, wfr[(14+nc)*64 + lane], acc[nc]);
        }
        #pragma unroll
        for (int nc = 0; nc < 4; ++nc)
            #pragma unroll
            for (int r = 0; r < 4; ++r)
                aw[(q*4+r)*72 + nc*16 + m16] = f2bf(fmaxf(acc[nc][r], 0.f));

        // ---- color L3: 64 -> 64, relu ----
        short8 a30 = *(const short8*)(aw + m16*72 + q*8);
        short8 a31 = *(const short8*)(aw + m16*72 + 32 + q*8);
        #pragma unroll
        for (int nc = 0; nc < 4; ++nc) {
            const float b = blds[208 + nc*16 + m16];
            acc[nc] = (f32x4){b,b,b,b};
            acc[nc] = MFMA(a30, wfr[(18+nc)*64 + lane], acc[nc]);
            acc[nc] = MFMA(a31, wfr[(22+nc)*64 + lane], acc[nc]);
        }
        #pragma unroll
        for (int nc = 0; nc < 4; ++nc)
            #pragma unroll
            for (int r = 0; r < 4; ++r)
                aw[(q*4+r)*72 + nc*16 + m16] = f2bf(fmaxf(acc[nc][r], 0.f));

        // ---- color L4: 64 -> 3 (padded to 16), sigmoid ----
        short8 a40 = *(const short8*)(aw + m16*72 + q*8);
        short8 a41 = *(const short8*)(aw + m16*72 + 32 + q*8);
        f32x4 c4v;
        { const float b = blds[272 + m16]; c4v = (f32x4){b,b,b,b}; }
        c4v = MFMA(a40, wfr[26*64 + lane], c4v);
        c4v = MFMA(a41, wfr[27*64 + lane], c4v);
        if (m16 < 3) {
            #pragma unroll
            for (int r = 0; r < 4; ++r)
                out[NPTS + 3*(p0g + q*4 + r) + m16] = 1.f / (1.f + expf(-c4v[r]));
        }
    }
}

extern "C" void kernel_launch(void* const* d_in, const int* in_sizes, int n_in,
                              void* d_out, int out_size, void* d_ws, size_t ws_size,
                              hipStream_t stream)
{
    // RES must bit-match numpy: floor(16 * b**l) in f64, b = exp((ln512-ln16)/15).
    ResArr res;
    const double b = exp((log(512.0) - log(16.0)) / 15.0);
    for (int l = 0; l < NLVL; ++l)
        res.r[l] = (float)floor(16.0 * pow(b, (double)l));

    // oct arrays for levels 0..6: dim = res+1
    QuadInfo qi;
    int ncell = 0;
    for (int l = 0; l < NQ; ++l) {
        const int D = (int)res.r[l] + 1;
        qi.dim[l] = D;
        qi.off[l] = ncell;
        ncell += D*D*D;
    }
    const int ncb   = (ncell + 255) / 256;     // oct-build blocks (2125)
    const int tailn = (ncb + 1 + 7) / 8;       // tail slots per XCD (266)
    const int smax  = 1152 + tailn;            // 1418
    const int grid  = smax * 8;                // 11344

    // ws: featws 16.8MB | oct (543,884*32B = 17.4MB) | wpk 28KB | bpk 1.2KB
    unsigned*       featws = (unsigned*)d_ws;
    uint4*          oct    = (uint4*)((char*)d_ws + (size_t)NLVL * NPTS * 4);
    unsigned short* wpk    = (unsigned short*)((char*)oct + (size_t)ncell * 32);
    float*          bpk    = (float*)((char*)wpk + 28 * 512 * 2);

    fused_encode_k<<<grid, 256, 0, stream>>>(
        (const float*)d_in[0],   // coords
        (const float*)d_in[2],   // embeddings
        oct, featws,
        (const float*)d_in[3],  (const float*)d_in[4],
        (const float*)d_in[5],  (const float*)d_in[6],
        (const float*)d_in[7],  (const float*)d_in[8],
        (const float*)d_in[9],  (const float*)d_in[10],
        (const float*)d_in[11], (const float*)d_in[12],
        (const float*)d_in[13], (const float*)d_in[14],
        wpk, bpk, res, qi, ncell, ncb, tailn);

    mlp_mfma_k<<<NPTS/TPB, 256, 0, stream>>>(
        featws, oct,
        (const float*)d_in[0],   // coords
        wpk, bpk,
        (const float*)d_in[1],   // directions
        (float*)d_out,
        res, qi);
}

// Round 5
// 226.009 us; speedup vs baseline: 1.1451x; 1.0157x over previous
//
#include <hip/hip_runtime.h>
#include <cmath>

#define NPTS 262144
#define NLVL 16
#define TBL  524288u
#define TMASK 524287u
#define TPB  512   // points per block (k2): 8 waves, 2 blocks/CU
#define NQ   7     // levels 0..6 oct-densified

typedef __attribute__((ext_vector_type(8))) short short8;
typedef __attribute__((ext_vector_type(4))) float f32x4;

struct ResArr { float r[NLVL]; };
struct QuadInfo { int off[NQ]; int dim[NQ]; };   // off in 32B oct-entry units

__device__ __forceinline__ unsigned short f2bf(float f) {
    union { float f; unsigned u; } v; v.f = f;
    unsigned r = v.u + 0x7FFFu + ((v.u >> 16) & 1u);   // RNE
    return (unsigned short)(r >> 16);
}
__device__ __forceinline__ float blo(unsigned u) {
    union { unsigned v; float f; } x; x.v = u << 16; return x.f;
}
__device__ __forceinline__ float bhi(unsigned u) {
    union { unsigned v; float f; } x; x.v = u & 0xffff0000u; return x.f;
}
__device__ __forceinline__ unsigned packbf(float a, float b) {
    return (unsigned)f2bf(a) | ((unsigned)f2bf(b) << 16);
}

#define MFMA(a,b,c) __builtin_amdgcn_mfma_f32_16x16x32_bf16((a),(b),(c),0,0,0)

// ---------------------------------------------------------------------------
// Kernel 1 (fused): hash-grid encode for levels 7..15 + oct BUILD for levels
// 0..6 + weight/bias pack, all in one request stream. (unchanged this round:
// ~86us at ~84% of the 13.1 req/cy/XCD ceiling, gather count at floor)
// ---------------------------------------------------------------------------
__global__ __launch_bounds__(256) void fused_encode_k(
    const float* __restrict__ coords,
    const float* __restrict__ emb,
    uint4* __restrict__ oct,
    unsigned* __restrict__ featws,
    const float* __restrict__ dw1, const float* __restrict__ db1,
    const float* __restrict__ dw2, const float* __restrict__ db2,
    const float* __restrict__ cw1, const float* __restrict__ cb1,
    const float* __restrict__ cw2, const float* __restrict__ cb2,
    const float* __restrict__ cw3, const float* __restrict__ cb3,
    const float* __restrict__ cw4, const float* __restrict__ cb4,
    unsigned short* __restrict__ wpk, float* __restrict__ bpk,
    ResArr res, QuadInfo qi, int ncell, int ncb, int tailn)
{
    const int tid = threadIdx.x;
    const int b   = blockIdx.x;
    const int xcd = b & 7;
    const int s   = b >> 3;

    if (s < 1152) {
        // -------- hashed path (levels 7..15), x-parity pairing --------
        int l, p;
        if (s < 1024) {
            l = 7 + xcd;
            p = s * 256 + tid;
        } else {
            l = 15;
            p = xcd * 32768 + (s - 1024) * 256 + tid;
        }

        const float cx = coords[3*p], cy = coords[3*p+1], cz = coords[3*p+2];
        const float r = res.r[l];
        const float px = cx*r, py = cy*r, pz = cz*r;
        const float fpx = floorf(px), fpy = floorf(py), fpz = floorf(pz);
        const float fx = px-fpx, fy = py-fpy, fz = pz-fpz;
        const unsigned ix=(unsigned)fpx, iy=(unsigned)fpy, iz=(unsigned)fpz;
        const unsigned hy0=iy*2654435761u, hy1=(iy+1u)*2654435761u;
        const unsigned hz0=iz*805459861u,  hz1=(iz+1u)*805459861u;
        const unsigned base  = (unsigned)l * TBL;          // float2 units
        const unsigned base4 = (unsigned)l * (TBL >> 1);   // float4 units
        const float2* __restrict__ emb2 = (const float2*)emb;
        const float4* __restrict__ emb4 = (const float4*)emb;

        const unsigned m = ix ^ (ix + 1u);                 // 1 iff ix even
        const unsigned h00 = (ix^hy0^hz0) & TMASK;
        const unsigned h01 = (ix^hy0^hz1) & TMASK;
        const unsigned h10 = (ix^hy1^hz0) & TMASK;
        const unsigned h11 = (ix^hy1^hz1) & TMASK;

        // pair loads: float4 at h>>1 = entries {h&~1, h|1}
        const float4 p00 = emb4[base4 + (h00 >> 1)];
        const float4 p01 = emb4[base4 + (h01 >> 1)];
        const float4 p10 = emb4[base4 + (h10 >> 1)];
        const float4 p11 = emb4[base4 + (h11 >> 1)];

        // x0 corner = half selected by h&1; x1 corner = other half (iff m==1)
        float2 f000, f001, f010, f011, f100, f101, f110, f111;
        f000.x = (h00&1) ? p00.z : p00.x;  f000.y = (h00&1) ? p00.w : p00.y;
        f001.x = (h01&1) ? p01.z : p01.x;  f001.y = (h01&1) ? p01.w : p01.y;
        f010.x = (h10&1) ? p10.z : p10.x;  f010.y = (h10&1) ? p10.w : p10.y;
        f011.x = (h11&1) ? p11.z : p11.x;  f011.y = (h11&1) ? p11.w : p11.y;
        f100.x = (h00&1) ? p00.x : p00.z;  f100.y = (h00&1) ? p00.y : p00.w;
        f101.x = (h01&1) ? p01.x : p01.z;  f101.y = (h01&1) ? p01.y : p01.w;
        f110.x = (h10&1) ? p10.x : p10.z;  f110.y = (h10&1) ? p10.y : p10.w;
        f111.x = (h11&1) ? p11.x : p11.z;  f111.y = (h11&1) ? p11.y : p11.w;

        if (m != 1u) {
            // odd-x lanes: true x1 corners are h^m, not in the pair
            f100 = emb2[base + ((h00 ^ m) & TMASK)];
            f101 = emb2[base + ((h01 ^ m) & TMASK)];
            f110 = emb2[base + ((h10 ^ m) & TMASK)];
            f111 = emb2[base + ((h11 ^ m) & TMASK)];
        }

        const float wx0=1.f-fx, wy0=1.f-fy, wz0=1.f-fz;
        float o0, o1;
        o0 = wx0*wy0*wz0*f000.x;                 o1 = wx0*wy0*wz0*f000.y;
        o0 = fmaf(wx0*wy0*fz,  f001.x, o0);      o1 = fmaf(wx0*wy0*fz,  f001.y, o1);
        o0 = fmaf(wx0*fy*wz0,  f010.x, o0);      o1 = fmaf(wx0*fy*wz0,  f010.y, o1);
        o0 = fmaf(wx0*fy*fz,   f011.x, o0);      o1 = fmaf(wx0*fy*fz,   f011.y, o1);
        o0 = fmaf(fx*wy0*wz0,  f100.x, o0);      o1 = fmaf(fx*wy0*wz0,  f100.y, o1);
        o0 = fmaf(fx*wy0*fz,   f101.x, o0);      o1 = fmaf(fx*wy0*fz,   f101.y, o1);
        o0 = fmaf(fx*fy*wz0,   f110.x, o0);      o1 = fmaf(fx*fy*wz0,   f110.y, o1);
        o0 = fmaf(fx*fy*fz,    f111.x, o0);      o1 = fmaf(fx*fy*fz,    f111.y, o1);

        featws[(size_t)l * NPTS + p] = packbf(o0, o1);
    } else {
        const int rank = xcd * tailn + (s - 1152);
        if (rank < ncb) {
            // -------- oct build --------
            const int gcell = rank * 256 + tid;
            if (gcell >= ncell) return;

            int l = 0;
            #pragma unroll
            for (int j = 1; j < NQ; ++j) if (gcell >= qi.off[j]) l = j;
            const int off = qi.off[l];
            const int D   = qi.dim[l];
            const int t   = gcell - off;
            const int DD  = D*D;

            const unsigned z = (unsigned)t % (unsigned)D;
            const unsigned rem = (unsigned)t / (unsigned)D;
            const unsigned y = rem % (unsigned)D;
            const unsigned x = rem / (unsigned)D;

            const float2* __restrict__ emb2 = (const float2*)emb;
            const unsigned base = (unsigned)l * TBL;
            const unsigned hy0 = y*2654435761u, hy1 = (y+1u)*2654435761u;
            const unsigned hz0 = z*805459861u,  hz1 = (z+1u)*805459861u;

            const float2 a = emb2[base + ((x^hy0^hz0)&TMASK)];
            const float2 bb= emb2[base + ((x^hy0^hz1)&TMASK)];
            const float2 c = emb2[base + ((x^hy1^hz0)&TMASK)];
            const float2 d = emb2[base + ((x^hy1^hz1)&TMASK)];

            uint4 q;
            q.x = packbf(a.x, a.y);
            q.y = packbf(bb.x, bb.y);
            q.z = packbf(c.x, c.y);
            q.w = packbf(d.x, d.y);

            const int e = off + t;
            oct[2*e] = q;                          // lo half of cell (x,y,z)
            if (t >= DD)
                oct[2*(e - DD) + 1] = q;           // hi half of cell (x-1,y,z)
        } else if (rank == ncb) {
            // -------- weight/bias pack --------
            const int wid  = tid >> 6;
            const int lane = tid & 63;
            const int m16  = lane & 15;
            const int q    = lane >> 4;
            const unsigned char MAT[28] = {0,0,0,0, 1,1, 2,2,2,2, 3,3,3,3,3,3,3,3, 4,4,4,4,4,4,4,4, 5,5};
            const unsigned char K0 [28] = {0,0,0,0, 0,32, 0,0,0,0, 0,0,0,0,32,32,32,32, 0,0,0,0,32,32,32,32, 0,32};
            const unsigned char N0 [28] = {0,16,32,48, 0,0, 0,16,32,48, 0,16,32,48,0,16,32,48, 0,16,32,48,0,16,32,48, 0,0};
            #pragma unroll
            for (int s2 = 0; s2 < 28; ++s2) {
                if ((s2 & 3) == wid) {
                    const int mat = MAT[s2];
                    const float* src = mat==0?dw1 : mat==1?dw2 : mat==2?cw1 : mat==3?cw2 : mat==4?cw3 : cw4;
                    const int fan = (mat==1) ? 16 : (mat==5) ? 3 : 64;
                    const int k = (int)K0[s2] + q*8;
                    const int n = (int)N0[s2] + m16;
                    unsigned short u[8];
                    #pragma unroll
                    for (int j = 0; j < 8; ++j) {
                        float v = 0.f;
                        if (mat != 5 || n < 3) v = src[(k+j)*fan + n];
                        u[j] = f2bf(v);
                    }
                    unsigned* w32 = (unsigned*)(wpk + s2*512 + lane*8);
                    w32[0] = (unsigned)u[0] | ((unsigned)u[1] << 16);
                    w32[1] = (unsigned)u[2] | ((unsigned)u[3] << 16);
                    w32[2] = (unsigned)u[4] | ((unsigned)u[5] << 16);
                    w32[3] = (unsigned)u[6] | ((unsigned)u[7] << 16);
                }
            }
            {
                int t = tid;
                if      (t <  64) bpk[t] = db1[t];
                else if (t <  80) bpk[t] = db2[t-64];
                else if (t < 144) bpk[t] = cb1[t-80];
                else if (t < 208) bpk[t] = cb2[t-144];
            }
            if (tid < 80) {
                int t = tid + 208;
                if (t < 272) bpk[t] = cb3[t-208];
                else         bpk[t] = (t-272 < 3) ? cb4[t-272] : 0.f;
            }
        }
    }
}

// ---------------------------------------------------------------------------
// Kernel 2: oct consume (levels 0..6) + MFMA MLP chain.
// R5: 512 pts/block, 8 waves, __launch_bounds__(512,4) -> 2 blocks/CU =
// 16 waves/CU (was 12) for the latency chain; featO packed stride-7;
// global A-frag dwords (levels 7..15) prefetched one iteration ahead.
// LDS = 28.7K wlds + 18.4K actL + 14.3K featO + 1.1K blds = 62.6KB.
// ---------------------------------------------------------------------------
__global__ __launch_bounds__(512, 4) void mlp_mfma_k(
    const unsigned* __restrict__ featws,
    const uint4* __restrict__ oct,
    const float* __restrict__ coords,
    const unsigned short* __restrict__ wpk,
    const float* __restrict__ bpk,
    const float* __restrict__ dirs,
    float* __restrict__ out,
    ResArr res, QuadInfo qi)
{
    const int tid  = threadIdx.x;
    const int wid  = tid >> 6;          // 0..7
    const int lane = tid & 63;
    const int m16  = lane & 15;
    const int q    = lane >> 4;

    __shared__ __align__(16) unsigned short wlds[28 * 512];
    __shared__ float blds[288];
    __shared__ __align__(16) unsigned short actL[8 * 16 * 72]; // per-wave [16][64+8] bf16
    __shared__ unsigned featO[TPB * 7];                        // [pt][lvl 0..6], stride 7

    {
        uint4* dst = (uint4*)wlds;
        const uint4* srcv = (const uint4*)wpk;   // 1792 uint4
        #pragma unroll
        for (int j = 0; j < 4; ++j) {
            const int idx = j*512 + tid;
            if (idx < 1792) dst[idx] = srcv[idx];
        }
        if (tid < 288) blds[tid] = bpk[tid];
    }

    const int pbase = blockIdx.x * TPB;

    // ---- prefetch iter-0 global A-frag dwords (levels 7..15) ----
    unsigned g0, g1, g2, g3;
    {
        const int pg = pbase + wid*16 + m16;     // tile = wid at iter 0
        const int l0 = q*4;
        g0 = (l0+0 >= NQ) ? featws[(size_t)(l0+0) * NPTS + pg] : 0u;
        g1 = (l0+1 >= NQ) ? featws[(size_t)(l0+1) * NPTS + pg] : 0u;
        g2 = (l0+2 >= NQ) ? featws[(size_t)(l0+2) * NPTS + pg] : 0u;
        g3 = (l0+3 >= NQ) ? featws[(size_t)(l0+3) * NPTS + pg] : 0u;
    }

    // ---- oct consume: levels 0..6 for point pbase+tid ----
    {
        const int p = pbase + tid;
        const float cx = coords[3*p], cy = coords[3*p+1], cz = coords[3*p+2];
        #pragma unroll
        for (int l = 0; l < NQ; ++l) {
            const float r = res.r[l];
            const float px = cx*r, py = cy*r, pz = cz*r;
            const float fpx = floorf(px), fpy = floorf(py), fpz = floorf(pz);
            const float fx = px-fpx, fy = py-fpy, fz = pz-fpz;
            const int ix=(int)fpx, iy=(int)fpy, iz=(int)fpz;
            const int D = qi.dim[l];
            const int v0 = qi.off[l] + (ix*D + iy)*D + iz;
            const uint4 qA = oct[2*v0];
            const uint4 qB = oct[2*v0 + 1];
            const float wx0=1.f-fx, wy0=1.f-fy, wz0=1.f-fz;
            const float w000=wx0*wy0*wz0, w001=wx0*wy0*fz;
            const float w010=wx0*fy*wz0,  w011=wx0*fy*fz;
            const float w100=fx*wy0*wz0,  w101=fx*wy0*fz;
            const float w110=fx*fy*wz0,   w111=fx*fy*fz;
            float o0, o1;
            o0 = w000*blo(qA.x);              o1 = w000*bhi(qA.x);
            o0 = fmaf(w001, blo(qA.y), o0);   o1 = fmaf(w001, bhi(qA.y), o1);
            o0 = fmaf(w010, blo(qA.z), o0);   o1 = fmaf(w010, bhi(qA.z), o1);
            o0 = fmaf(w011, blo(qA.w), o0);   o1 = fmaf(w011, bhi(qA.w), o1);
            o0 = fmaf(w100, blo(qB.x), o0);   o1 = fmaf(w100, bhi(qB.x), o1);
            o0 = fmaf(w101, blo(qB.y), o0);   o1 = fmaf(w101, bhi(qB.y), o1);
            o0 = fmaf(w110, blo(qB.z), o0);   o1 = fmaf(w110, bhi(qB.z), o1);
            o0 = fmaf(w111, blo(qB.w), o0);   o1 = fmaf(w111, bhi(qB.w), o1);
            featO[tid*7 + l] = packbf(o0, o1);
        }
    }
    __syncthreads();

    unsigned short* aw = actL + wid*1152;     // 16 x 72
    const short8* wfr = (const short8*)wlds;  // B(s) = wfr[s*64 + lane]

    #pragma unroll 1
    for (int iter = 0; iter < 4; ++iter) {
        const int tile = wid + 8*iter;
        const int loc0 = tile*16;
        const int p0g  = pbase + loc0;

        // ---- prefetch next iter's global A-frag dwords ----
        unsigned n0 = 0u, n1 = 0u, n2 = 0u, n3 = 0u;
        if (iter < 3) {
            const int pg = pbase + (wid + 8*(iter+1))*16 + m16;
            const int l0 = q*4;
            n0 = (l0+0 >= NQ) ? featws[(size_t)(l0+0) * NPTS + pg] : 0u;
            n1 = (l0+1 >= NQ) ? featws[(size_t)(l0+1) * NPTS + pg] : 0u;
            n2 = (l0+2 >= NQ) ? featws[(size_t)(l0+2) * NPTS + pg] : 0u;
            n3 = (l0+3 >= NQ) ? featws[(size_t)(l0+3) * NPTS + pg] : 0u;
        }

        // ---- A-frag for density L1: levels q*4..q*4+3 of point p0g+m16 ----
        union { unsigned u[4]; short8 s; } af;
        {
            const int l0 = q*4;
            const int rowb = (loc0 + m16) * 7;
            af.u[0] = (l0+0 < NQ) ? featO[rowb + l0+0] : g0;
            af.u[1] = (l0+1 < NQ) ? featO[rowb + l0+1] : g1;
            af.u[2] = (l0+2 < NQ) ? featO[rowb + l0+2] : g2;
            af.u[3] = (l0+3 < NQ) ? featO[rowb + l0+3] : g3;
        }
        const short8 a0 = af.s;

        // ---- density L1: feat(32) -> 64, relu ----
        f32x4 acc[4];
        #pragma unroll
        for (int nc = 0; nc < 4; ++nc) {
            const float b = blds[nc*16 + m16];
            acc[nc] = (f32x4){b,b,b,b};
            acc[nc] = MFMA(a0, wfr[nc*64 + lane], acc[nc]);
        }
        #pragma unroll
        for (int nc = 0; nc < 4; ++nc)
            #pragma unroll
            for (int r = 0; r < 4; ++r)
                aw[(q*4+r)*72 + nc*16 + m16] = f2bf(fmaxf(acc[nc][r], 0.f));

        // ---- density L2: 64 -> 16 (no act) ----
        short8 ad0 = *(const short8*)(aw + m16*72 + q*8);
        short8 ad1 = *(const short8*)(aw + m16*72 + 32 + q*8);
        f32x4 dob;
        { const float b = blds[64 + m16]; dob = (f32x4){b,b,b,b}; }
        dob = MFMA(ad0, wfr[4*64 + lane], dob);
        dob = MFMA(ad1, wfr[5*64 + lane], dob);

        if (m16 == 0) {
            #pragma unroll
            for (int r = 0; r < 4; ++r) out[p0g + q*4 + r] = expf(dob[r]);
        }

        // ---- build inp = [SH(16) | dob(16)] ----
        #pragma unroll
        for (int r = 0; r < 4; ++r)
            aw[(q*4+r)*72 + 16 + m16] = f2bf(dob[r]);
        {
            const int pg = p0g + m16;
            const float dx0 = dirs[3*pg], dy0 = dirs[3*pg+1], dz0 = dirs[3*pg+2];
            const float inv = 1.f / sqrtf(dx0*dx0 + dy0*dy0 + dz0*dz0);
            float x = dx0*inv, y = dy0*inv, z = dz0*inv;
            x = ((x+1.f)*0.5f)*2.f - 1.f;
            y = ((y+1.f)*0.5f)*2.f - 1.f;
            z = ((z+1.f)*0.5f)*2.f - 1.f;
            float s0, s1, s2, s3;
            switch (q) {
            case 0: s0 = 0.28209479177387814f;
                    s1 = -0.48860251190291987f*y;
                    s2 =  0.48860251190291987f*z;
                    s3 = -0.48860251190291987f*x; break;
            case 1: s0 =  1.0925484305920792f*x*y;
                    s1 = -1.0925484305920792f*y*z;
                    s2 =  0.94617469575756f*z*z - 0.31539156525252f;
                    s3 = -1.0925484305920792f*x*z; break;
            case 2: s0 =  0.5462742152960396f*(x*x - y*y);
                    s1 =  0.5900435899266435f*y*(-3.f*x*x + y*y);
                    s2 =  2.890611442640554f*x*y*z;
                    s3 =  0.4570457994644657f*y*(1.f - 5.f*z*z); break;
            default:s0 =  0.3731763325901154f*z*(5.f*z*z - 3.f);
                    s1 =  0.4570457994644657f*x*(1.f - 5.f*z*z);
                    s2 =  1.445305721320277f*z*(x*x - y*y);
                    s3 =  0.5900435899266435f*x*(x*x - 3.f*y*y); break;
            }
            unsigned* ip = (unsigned*)(aw + m16*72 + q*4);
            ip[0] = packbf(s0, s1);
            ip[1] = packbf(s2, s3);
        }

        // ---- color L1: inp(32) -> 64, relu ----
        short8 ac0 = *(const short8*)(aw + m16*72 + q*8);
        #pragma unroll
        for (int nc = 0; nc < 4; ++nc) {
            const float b = blds[80 + nc*16 + m16];
            acc[nc] = (f32x4){b,b,b,b};
            acc[nc] = MFMA(ac0, wfr[(6+nc)*64 + lane], acc[nc]);
        }
        #pragma unroll
        for (int nc = 0; nc < 4; ++nc)
            #pragma unroll
            for (int r = 0; r < 4; ++r)
                aw[(q*4+r)*72 + nc*16 + m16] = f2bf(fmaxf(acc[nc][r], 0.f));

        // ---- color L2: 64 -> 64, relu ----
        short8 a20 = *(const short8*)(aw + m16*72 + q*8);
        short8 a21 = *(const short8*)(aw + m16*72 + 32 + q*8);
        #pragma unroll
        for (int nc = 0; nc < 4; ++nc) {
            const float b = blds[144 + nc*16 + m16];
            acc[nc] = (f32x4){b,b,b,b};
            acc[nc] = MFMA(a20, wfr[(10+nc)*64 + lane], acc[nc]);
            acc[nc] = MFMA(a21, wfr[(14+nc)*64 + lane], acc[nc]);
        }
        #pragma unroll
        for (int nc = 0; nc < 4; ++nc)
            #pragma unroll
            for (int r = 0; r < 4; ++r)
                aw[(q*4+r)*72 + nc*16 + m16] = f2bf(fmaxf(acc[nc][r], 0.f));

        // ---- color L3: 64 -> 64, relu ----
        short8 a30 = *(const short8*)(aw + m16*72 + q*8);
        short8 a31 = *(const short8*)(aw + m16*72 + 32 + q*8);
        #pragma unroll
        for (int nc = 0; nc < 4; ++nc) {
            const float b = blds[208 + nc*16 + m16];
            acc[nc] = (f32x4){b,b,b,b};
            acc[nc] = MFMA(a30, wfr[(18+nc)*64 + lane], acc[nc]);
            acc[nc] = MFMA(a31, wfr[(22+nc)*64 + lane], acc[nc]);
        }
        #pragma unroll
        for (int nc = 0; nc < 4; ++nc)
            #pragma unroll
            for (int r = 0; r < 4; ++r)
                aw[(q*4+r)*72 + nc*16 + m16] = f2bf(fmaxf(acc[nc][r], 0.f));

        // ---- color L4: 64 -> 3 (padded to 16), sigmoid ----
        short8 a40 = *(const short8*)(aw + m16*72 + q*8);
        short8 a41 = *(const short8*)(aw + m16*72 + 32 + q*8);
        f32x4 c4v;
        { const float b = blds[272 + m16]; c4v = (f32x4){b,b,b,b}; }
        c4v = MFMA(a40, wfr[26*64 + lane], c4v);
        c4v = MFMA(a41, wfr[27*64 + lane], c4v);
        if (m16 < 3) {
            #pragma unroll
            for (int r = 0; r < 4; ++r)
                out[NPTS + 3*(p0g + q*4 + r) + m16] = 1.f / (1.f + expf(-c4v[r]));
        }

        // rotate prefetch
        g0 = n0; g1 = n1; g2 = n2; g3 = n3;
    }
}

extern "C" void kernel_launch(void* const* d_in, const int* in_sizes, int n_in,
                              void* d_out, int out_size, void* d_ws, size_t ws_size,
                              hipStream_t stream)
{
    // RES must bit-match numpy: floor(16 * b**l) in f64, b = exp((ln512-ln16)/15).
    ResArr res;
    const double b = exp((log(512.0) - log(16.0)) / 15.0);
    for (int l = 0; l < NLVL; ++l)
        res.r[l] = (float)floor(16.0 * pow(b, (double)l));

    // oct arrays for levels 0..6: dim = res+1
    QuadInfo qi;
    int ncell = 0;
    for (int l = 0; l < NQ; ++l) {
        const int D = (int)res.r[l] + 1;
        qi.dim[l] = D;
        qi.off[l] = ncell;
        ncell += D*D*D;
    }
    const int ncb   = (ncell + 255) / 256;     // oct-build blocks (2125)
    const int tailn = (ncb + 1 + 7) / 8;       // tail slots per XCD (266)
    const int smax  = 1152 + tailn;            // 1418
    const int grid  = smax * 8;                // 11344

    // ws: featws 16.8MB | oct (543,884*32B = 17.4MB) | wpk 28KB | bpk 1.2KB
    unsigned*       featws = (unsigned*)d_ws;
    uint4*          oct    = (uint4*)((char*)d_ws + (size_t)NLVL * NPTS * 4);
    unsigned short* wpk    = (unsigned short*)((char*)oct + (size_t)ncell * 32);
    float*          bpk    = (float*)((char*)wpk + 28 * 512 * 2);

    fused_encode_k<<<grid, 256, 0, stream>>>(
        (const float*)d_in[0],   // coords
        (const float*)d_in[2],   // embeddings
        oct, featws,
        (const float*)d_in[3],  (const float*)d_in[4],
        (const float*)d_in[5],  (const float*)d_in[6],
        (const float*)d_in[7],  (const float*)d_in[8],
        (const float*)d_in[9],  (const float*)d_in[10],
        (const float*)d_in[11], (const float*)d_in[12],
        (const float*)d_in[13], (const float*)d_in[14],
        wpk, bpk, res, qi, ncell, ncb, tailn);

    mlp_mfma_k<<<NPTS/TPB, 512, 0, stream>>>(
        featws, oct,
        (const float*)d_in[0],   // coords
        wpk, bpk,
        (const float*)d_in[1],   // directions
        (float*)d_out,
        res, qi);
}